// Round 11
// baseline (645.285 us; speedup 1.0000x reference)
//
#include <hip/hip_runtime.h>
#include <hip/hip_bf16.h>
#include <math.h>

#define Bb 2
#define Dm 192
#define NHh 8
#define HDd 24
#define N0 9216
#define N1 2304
#define LSEQ 11520
#define FFD 256
#define Mrows (Bb*LSEQ)            // 23040

typedef __attribute__((ext_vector_type(8))) short short8;
typedef __attribute__((ext_vector_type(4))) float f32x4;

// ---------------- workspace layout (float offsets) ----------------
#define F_OUT 0                         // fp32 [23040][192]
#define F_PRE (F_OUT + 4423680)         // fp32 conv-out/GN src; in-loop: V buffer A
#define F_POS (F_PRE + 4423680)         // fp32 [11520][192]
#define F_LOC (F_POS + 2211840)         // fp32 [23040][64][2]   (early: FEATB bf16)
#define F_AW  (F_LOC + 2949120)         // fp32 [23040][64]      (early: CWB bf16)
#define F_QB  (F_AW + 1474560)          // bf16 [23040][192]  (Q, pre-loop only)
#define F_OB  (F_QB + 2211840)          // bf16 [23040][192]  (pre-loop only)
#define F_AH  (F_OB + 2211840)          // bf16 [23040][192] ATT (early: GPART)
#define F_WT16 (F_AH + 2949120)         // bf16 weights, 6*208896 elems
#define F_BC  (F_WT16 + 626688)         // fp32 [6][192] concat so|aw bias
#define F_GNS (F_BC + 1152)             // fp32 group-norm stats (128*2)
#define F_V2  (F_GNS + 256)             // fp32 [23040][192]  V buffer B
// end ~ 29.1M floats ~= 116 MB (ws = 256 MiB)

// per-layer WT16 sub-offsets (bf16 elems)
#define WL_STRIDE 208896
#define WL_SOAW 0
#define WL_VP   36864
#define WL_OP   73728
#define WL_L1   110592
#define WL_L2   159744

__device__ inline __hip_bfloat16 f2b(float f) { return __float2bfloat16(f); }
__device__ inline unsigned short f2bu(float f) {
    __hip_bfloat16 h = __float2bfloat16(f);
    return *reinterpret_cast<unsigned short*>(&h);
}

// -------------------- pos embed --------------------
__global__ void k_pos(float* pos, const float* level_embed) {
    int idx = blockIdx.x * 256 + threadIdx.x;
    if (idx >= LSEQ * Dm) return;
    int t = idx / Dm, d = idx % Dm;
    int lvl, row, col, H, W;
    if (t < N0) { lvl = 0; H = 96; W = 96; row = t / 96; col = t % 96; }
    else        { lvl = 1; H = 48; W = 48; int tl = t - N0; row = tl / 48; col = tl % 48; }
    int k = d % 96;
    float v;
    if (d < 96) v = (row + 0.5f) / ((float)H + 1e-6f) * 6.2831853071795864f;
    else        v = (col + 0.5f) / ((float)W + 1e-6f) * 6.2831853071795864f;
    float expo = (float)(k - (k & 1)) / 96.0f;
    float tm = exp2f(expo * 13.287712379549449f);   // 10000^expo
    float p = v / tm;
    float pe = (k & 1) ? cosf(p) : sinf(p);
    pos[idx] = pe + level_embed[lvl * Dm + d];
}

// -------------------- prep: transpose + bf16-convert encoder weights ----
__global__ void k_prep(const float* soW, const float* awW, const float* vpW,
        const float* opW, const float* l1W, const float* l2W,
        const float* sob, const float* awb,
        __hip_bfloat16* WT, float* BC) {
    int idx = blockIdx.x * 256 + threadIdx.x;
    if (idx < 6 * 192) {
        int i = idx / 192, n = idx % 192;
        BC[idx] = (n < 128) ? sob[i * 128 + n] : awb[i * 64 + (n - 128)];
    }
    if (idx >= 6 * WL_STRIDE) return;
    int i = idx / WL_STRIDE; int r = idx % WL_STRIDE;
    float v;
    if (r < 36864)       { int n = r / 192, k = r % 192;
        v = (n < 128) ? soW[((size_t)i * 192 + k) * 128 + n]
                      : awW[((size_t)i * 192 + k) * 64 + (n - 128)]; }
    else if (r < 73728)  { int q = r - 36864;  int n = q / 192, k = q % 192;
        v = vpW[((size_t)i * 192 + k) * 192 + n]; }
    else if (r < 110592) { int q = r - 73728;  int n = q / 192, k = q % 192;
        v = opW[((size_t)i * 192 + k) * 192 + n]; }
    else if (r < 159744) { int q = r - 110592; int n = q / 192, k = q % 192;
        v = l1W[((size_t)i * 192 + k) * 256 + n]; }
    else                 { int q = r - 159744; int n = q / 256, k = q % 256;
        v = l2W[((size_t)i * 256 + k) * 192 + n]; }
    WT[idx] = f2b(v);
}

// conv weights: proj_w is [o][c] which is exactly Bt[N][K] — just convert
__global__ void k_prepc(const float* w0, const float* w1, __hip_bfloat16* cwb) {
    int idx = blockIdx.x * 256 + threadIdx.x;
    if (idx >= 2 * 36864) return;
    const float* w = (idx < 36864) ? w0 : w1;
    int r = idx % 36864;
    cwb[idx] = f2b(w[r]);
}

// -------------------- feature transpose [b][c][t] -> bf16 [t][c] ----------
__global__ void k_tf(const float* feat, __hip_bfloat16* out, int HW, int st) {
    __shared__ float tile[32][33];
    int t0 = blockIdx.x * 32, c0 = blockIdx.y * 32, b = blockIdx.z;
    int tx = threadIdx.x, ty = threadIdx.y;
    #pragma unroll
    for (int k = 0; k < 4; k++) {
        int c = c0 + ty + k * 8;
        tile[ty + k * 8][tx] = feat[((size_t)b * Dm + c) * HW + t0 + tx];
    }
    __syncthreads();
    #pragma unroll
    for (int k = 0; k < 4; k++) {
        int t = t0 + ty + k * 8;
        out[((size_t)b * LSEQ + st + t) * Dm + c0 + tx] = f2b(tile[tx][ty + k * 8]);
    }
}

// -------------------- GN partial sums (coalesced) --------------------
__global__ __launch_bounds__(192) void k_gnp(const float* __restrict__ pre,
        float* __restrict__ part) {
    int bid = blockIdx.x;                 // 0..239
    int b = bid / 120; int r = bid % 120;
    int l = (r >= 96) ? 1 : 0; int ch = l ? (r - 96) : r;
    int start = b * LSEQ + (l ? N0 : 0) + ch * 96;
    int d = threadIdx.x;
    float s = 0.f, sq = 0.f;
    for (int t = 0; t < 96; t++) {
        float x = pre[(size_t)(start + t) * Dm + d];
        s += x; sq += x * x;
    }
    __shared__ float ls[192], lq[192];
    ls[d] = s; lq[d] = sq;
    __syncthreads();
    if (d < 32) {
        float a = 0.f, b2 = 0.f;
        #pragma unroll
        for (int j = 0; j < 6; j++) { a += ls[d * 6 + j]; b2 += lq[d * 6 + j]; }
        part[((size_t)bid * 32 + d) * 2]     = a;
        part[((size_t)bid * 32 + d) * 2 + 1] = b2;
    }
}

__global__ void k_gnf(const float* __restrict__ part, float* __restrict__ gns) {
    int bid = blockIdx.x;                 // (b,l,g): 128
    int b = bid >> 6; int l = (bid >> 5) & 1; int g = bid & 31;
    int nch = l ? 24 : 96;
    int base = b * 120 + (l ? 96 : 0);
    int tid = threadIdx.x;
    float s = 0.f, q = 0.f;
    for (int c = tid; c < nch; c += 64) {
        s += part[((size_t)(base + c) * 32 + g) * 2];
        q += part[((size_t)(base + c) * 32 + g) * 2 + 1];
    }
    for (int m = 1; m < 64; m <<= 1) { s += __shfl_xor(s, m, 64); q += __shfl_xor(q, m, 64); }
    if (tid == 0) {
        float total = (float)((l ? N1 : N0) * 6);
        float mean = s / total;
        float var = q / total - mean * mean;
        gns[bid * 2] = mean;
        gns[bid * 2 + 1] = rsqrtf(var + 1e-5f);
    }
}

// -------------------- group norm apply: OUT f32 + O bf16 + Q bf16 ----------
__global__ void k_gnnorm(const float* srcp, const float* gns,
        const float* g0, const float* b0, const float* g1, const float* b1,
        const float* pos, float* out, __hip_bfloat16* ob, __hip_bfloat16* qb) {
    int idx = blockIdx.x * 256 + threadIdx.x;
    if (idx >= Bb * LSEQ * Dm) return;
    int d = idx % Dm;
    int t = (idx / Dm) % LSEQ;
    int l = (t < N0) ? 0 : 1;
    int g = d / 6;
    int b = idx / (Dm * LSEQ);
    int sid = ((b * 2 + l) * 32 + g) * 2;
    float mean = gns[sid], rstd = gns[sid + 1];
    float gg = l ? g1[d] : g0[d];
    float bbv = l ? b1[d] : b0[d];
    float v = (srcp[idx] - mean) * rstd * gg + bbv;
    out[idx] = v;
    ob[idx] = f2b(v);
    qb[idx] = f2b(v + pos[idx - (size_t)b * LSEQ * Dm]);
}

// -------------------- bf16 MFMA GEMM (conv path) --------------------------
template<int KSTEPS>
__global__ __launch_bounds__(256) void k_gemm(
        const __hip_bfloat16* __restrict__ A,
        const __hip_bfloat16* __restrict__ Bt,
        const float* __restrict__ bias,
        float* __restrict__ Cf, int N) {
    constexpr int K = KSTEPS * 32;
    int wid = threadIdx.x >> 6, lane = threadIdx.x & 63;
    int lg = lane >> 4, lr = lane & 15;
    int row0 = blockIdx.x * 64 + wid * 16;
    int col0 = blockIdx.y * 64;
    const short* a_base = (const short*)A + (size_t)(row0 + lr) * K + lg * 8;
    const short* b_base = (const short*)Bt + (size_t)(col0 + lr) * K + lg * 8;
    f32x4 acc[4] = {};
    #pragma unroll
    for (int kk = 0; kk < KSTEPS; kk++) {
        short8 af = *(const short8*)(a_base + kk * 32);
        #pragma unroll
        for (int n = 0; n < 4; n++) {
            short8 bfr = *(const short8*)(b_base + (size_t)n * 16 * K + kk * 32);
            acc[n] = __builtin_amdgcn_mfma_f32_16x16x32_bf16(af, bfr, acc[n], 0, 0, 0);
        }
    }
    #pragma unroll
    for (int n = 0; n < 4; n++) {
        int col = col0 + n * 16 + lr;
        float bv = bias[col];
        #pragma unroll
        for (int r = 0; r < 4; r++) {
            int row = row0 + lg * 4 + r;
            Cf[(size_t)row * N + col] = acc[n][r] + bv;
        }
    }
}

// ------------- layer-0 soaw + value-proj (BM=32, regs-held B) -------------
__global__ __launch_bounds__(192) void k_soawvp(
        const __hip_bfloat16* __restrict__ QB,
        const __hip_bfloat16* __restrict__ OB,
        const __hip_bfloat16* __restrict__ BtS,
        const __hip_bfloat16* __restrict__ BtV,
        const float* __restrict__ biasS,
        const float* __restrict__ biasV,
        float* __restrict__ LOC, float* __restrict__ AW,
        float* __restrict__ VF) {
    constexpr int K = 192;
    int wid = threadIdx.x >> 6, lane = threadIdx.x & 63;
    int lg = lane >> 4, lr = lane & 15;
    int row0 = blockIdx.x * 32;
    int col0 = wid * 64;
    int role = blockIdx.y;
    const short* A  = (const short*)(role ? OB : QB);
    const short* Bt = (const short*)(role ? BtV : BtS);
    const float* bias = role ? biasV : biasS;
    short8 bw[24];
    {
        const short* b_base = Bt + (size_t)(col0 + lr) * K + lg * 8;
        #pragma unroll
        for (int n = 0; n < 4; n++)
            #pragma unroll
            for (int kk = 0; kk < 6; kk++)
                bw[n * 6 + kk] = *(const short8*)(b_base + (size_t)n * 16 * K + kk * 32);
    }
    #pragma unroll
    for (int rg = 0; rg < 2; rg++) {
        const short* a_base = A + (size_t)(row0 + rg * 16 + lr) * K + lg * 8;
        f32x4 acc[4] = {};
        #pragma unroll
        for (int kk = 0; kk < 6; kk++) {
            short8 af = *(const short8*)(a_base + kk * 32);
            #pragma unroll
            for (int n = 0; n < 4; n++)
                acc[n] = __builtin_amdgcn_mfma_f32_16x16x32_bf16(af, bw[n * 6 + kk], acc[n], 0, 0, 0);
        }
        #pragma unroll
        for (int n = 0; n < 4; n++) {
            float bv = bias[col0 + n * 16 + lr];
            #pragma unroll
            for (int r = 0; r < 4; r++) acc[n][r] += bv;
        }
        int rbase = row0 + rg * 16;
        if (role) {
            #pragma unroll
            for (int n = 0; n < 4; n++) {
                int col = col0 + n * 16 + lr;
                #pragma unroll
                for (int r = 0; r < 4; r++)
                    VF[(size_t)(rbase + lg * 4 + r) * Dm + col] = acc[n][r];
            }
        } else if (wid == 2) {
            #pragma unroll
            for (int n = 0; n < 4; n++) {
                #pragma unroll
                for (int r = 0; r < 4; r++) {
                    float v = acc[n][r];
                    float m = v;
                    m = fmaxf(m, __shfl_xor(m, 1)); m = fmaxf(m, __shfl_xor(m, 2));
                    m = fmaxf(m, __shfl_xor(m, 4));
                    float e = expf(v - m);
                    float sm = e;
                    sm += __shfl_xor(sm, 1); sm += __shfl_xor(sm, 2); sm += __shfl_xor(sm, 4);
                    AW[(size_t)(rbase + lg * 4 + r) * 64 + n * 16 + lr] = e / sm;
                }
            }
        } else {
            #pragma unroll
            for (int r = 0; r < 4; r++) {
                int row = rbase + lg * 4 + r;
                int t = (row >= LSEQ) ? row - LSEQ : row;
                int rr, cc, Ht, Wt;
                if (t < N0) { Ht = 96; Wt = 96; rr = t / 96; cc = t % 96; }
                else        { Ht = 48; Wt = 48; int tl = t - N0; rr = tl / 48; cc = tl % 48; }
                float refx = (cc + 0.5f) / (float)Wt;
                float refy = (rr + 0.5f) / (float)Ht;
                #pragma unroll
                for (int n = 0; n < 4; n++) {
                    int col = col0 + n * 16 + lr;
                    int j = col >> 1, comp = col & 1;
                    float sc = (j & 4) ? 48.f : 96.f;
                    LOC[(size_t)row * 128 + col] = (comp ? refy : refx) + acc[n][r] / sc;
                }
            }
        }
    }
}

// -------------------- deformable sampling (fp32 V, vectorized) -------------
// block = 192 thr = 4 tokens x 48 lanes (8 heads x 6 d-quads)
__global__ __launch_bounds__(192) void k_sample(const float* __restrict__ V,
        const float* __restrict__ LOC, const float* __restrict__ AW,
        __hip_bfloat16* __restrict__ ATT) {
    __shared__ float aw_s[4][64];
    __shared__ float loc_s[4][128];
    int tid = threadIdx.x;
    int tg0 = blockIdx.x * 4;
    for (int idx = tid; idx < 256; idx += 192)
        aw_s[idx >> 6][idx & 63] = AW[(size_t)tg0 * 64 + idx];
    for (int idx = tid; idx < 512; idx += 192)
        loc_s[idx >> 7][idx & 127] = LOC[(size_t)tg0 * 128 + idx];
    __syncthreads();
    int tt = tid / 48, lane = tid - tt * 48;
    int h = lane / 6, dq = lane - h * 6;
    int tg = tg0 + tt;
    int b = (tg >= LSEQ) ? 1 : 0;
    const float* vb = V + (size_t)b * LSEQ * Dm + h * HDd + dq * 4;
    float a0 = 0.f, a1 = 0.f, a2 = 0.f, a3 = 0.f;
    #pragma unroll
    for (int lp = 0; lp < 8; lp++) {
        int l = lp >> 2;
        int Wl = l ? 48 : 96, Hl = l ? 48 : 96, st = l ? N0 : 0;
        float a  = aw_s[tt][h * 8 + lp];
        float lx = loc_s[tt][(h * 8 + lp) * 2];
        float ly = loc_s[tt][(h * 8 + lp) * 2 + 1];
        float x = lx * (float)Wl - 0.5f, y = ly * (float)Hl - 0.5f;
        float x0f = floorf(x), y0f = floorf(y);
        float wx = x - x0f, wy = y - y0f;
        int x0 = (int)x0f, y0 = (int)y0f;
        #pragma unroll
        for (int cy = 0; cy < 2; cy++) {
            int yi = y0 + cy;
            float wyv = cy ? wy : 1.f - wy;
            bool vy = (yi >= 0) && (yi < Hl);
            int yc = min(max(yi, 0), Hl - 1);
            #pragma unroll
            for (int cx = 0; cx < 2; cx++) {
                int xi = x0 + cx;
                float wv = (cx ? wx : 1.f - wx) * wyv;
                bool ok = vy && (xi >= 0) && (xi < Wl);
                int xc = min(max(xi, 0), Wl - 1);
                float cw = ok ? a * wv : 0.f;
                float4 g4 = *(const float4*)(vb + (size_t)(st + yc * Wl + xc) * Dm);
                a0 += cw * g4.x; a1 += cw * g4.y;
                a2 += cw * g4.z; a3 += cw * g4.w;
            }
        }
    }
    ushort4 o4;
    o4.x = f2bu(a0); o4.y = f2bu(a1); o4.z = f2bu(a2); o4.w = f2bu(a3);
    *(ushort4*)((unsigned short*)ATT + (size_t)tg * Dm + h * HDd + dq * 4) = o4;
}

// ------------- fused tail: op+LN1+FFN+LN2 (+ next-layer vp/soaw) ----------
// BM=32, 256 thr = 4 waves, shared-B interleave across 2 row-groups.
// Phase A: op GEMM + bias + residual + LN1 (ATT global -> ybf, yres regs)
// Phase B: ffn1 + ReLU -> hid
// Phase C: ffn2 + resid + LN2 -> OUT; (!LAST) ybf=y2 bf16, hid=y2+pos bf16
// Phase D (!LAST): D1 vp GEMM (ybf) -> Vout; D2 soaw GEMM (hid) -> AW/LOC
template<bool LAST>
__global__ __launch_bounds__(256) void k_tail(
        const __hip_bfloat16* __restrict__ ATT,
        float* __restrict__ LOC, float* __restrict__ AW,
        const __hip_bfloat16* __restrict__ BtOp, const float* __restrict__ bOp,
        const __hip_bfloat16* __restrict__ Bt1, const float* __restrict__ b1,
        const __hip_bfloat16* __restrict__ Bt2, const float* __restrict__ b2,
        const float* __restrict__ g1, const float* __restrict__ t1,
        const float* __restrict__ g2, const float* __restrict__ t2,
        const float* __restrict__ pos,
        float* __restrict__ OUTp,
        const __hip_bfloat16* __restrict__ BtS,
        const __hip_bfloat16* __restrict__ BtV,
        const float* __restrict__ biasS, const float* __restrict__ biasV,
        float* __restrict__ Vout) {
    __shared__ __align__(16) short ybf[32][200];   // att/y -> y2
    __shared__ __align__(16) short hid[32][264];   // hidden -> q
    __shared__ float ps[4][32], pq[4][32];
    int tid = threadIdx.x;
    int wid = tid >> 6, lane = tid & 63, lg = lane >> 4, lr = lane & 15;
    int row0 = blockIdx.x * 32;
    float yres[2][3][4];
    // ---- phase A: op GEMM (K=192, N=192) + bias + residual + LN1 ----
    {
        float resid[2][3][4];
        #pragma unroll
        for (int rg = 0; rg < 2; rg++)
            #pragma unroll
            for (int n = 0; n < 3; n++) {
                int col = wid * 48 + n * 16 + lr;
                #pragma unroll
                for (int r = 0; r < 4; r++)
                    resid[rg][n][r] = OUTp[(size_t)(row0 + rg * 16 + lg * 4 + r) * Dm + col];
            }
        const short* a0 = (const short*)ATT + (size_t)(row0 + lr) * 192 + lg * 8;
        const short* a1 = (const short*)ATT + (size_t)(row0 + 16 + lr) * 192 + lg * 8;
        const short* b_base = (const short*)BtOp + (size_t)(wid * 48 + lr) * 192 + lg * 8;
        f32x4 acc[2][3] = {};
        #pragma unroll
        for (int kk = 0; kk < 6; kk++) {
            short8 af0 = *(const short8*)(a0 + kk * 32);
            short8 af1 = *(const short8*)(a1 + kk * 32);
            #pragma unroll
            for (int n = 0; n < 3; n++) {
                short8 bfr = *(const short8*)(b_base + (size_t)n * 16 * 192 + kk * 32);
                acc[0][n] = __builtin_amdgcn_mfma_f32_16x16x32_bf16(af0, bfr, acc[0][n], 0, 0, 0);
                acc[1][n] = __builtin_amdgcn_mfma_f32_16x16x32_bf16(af1, bfr, acc[1][n], 0, 0, 0);
            }
        }
        #pragma unroll
        for (int rg = 0; rg < 2; rg++) {
            float s[4] = {0.f, 0.f, 0.f, 0.f}, q[4] = {0.f, 0.f, 0.f, 0.f};
            #pragma unroll
            for (int n = 0; n < 3; n++) {
                int col = wid * 48 + n * 16 + lr;
                float bv = bOp[col];
                #pragma unroll
                for (int r = 0; r < 4; r++) {
                    float v = acc[rg][n][r] + bv + resid[rg][n][r];
                    acc[rg][n][r] = v;
                    s[r] += v; q[r] += v * v;
                }
            }
            #pragma unroll
            for (int r = 0; r < 4; r++) {
                #pragma unroll
                for (int m = 1; m < 16; m <<= 1) {
                    s[r] += __shfl_xor(s[r], m); q[r] += __shfl_xor(q[r], m);
                }
            }
            if (lr == 0) {
                #pragma unroll
                for (int r = 0; r < 4; r++) {
                    ps[wid][rg * 16 + lg * 4 + r] = s[r];
                    pq[wid][rg * 16 + lg * 4 + r] = q[r];
                }
            }
        }
        __syncthreads();
        #pragma unroll
        for (int rg = 0; rg < 2; rg++) {
            float mean[4], rstd[4];
            #pragma unroll
            for (int r = 0; r < 4; r++) {
                int rl = rg * 16 + lg * 4 + r;
                float S = ps[0][rl] + ps[1][rl] + ps[2][rl] + ps[3][rl];
                float Q = pq[0][rl] + pq[1][rl] + pq[2][rl] + pq[3][rl];
                mean[r] = S * (1.f / Dm);
                float var = Q * (1.f / Dm) - mean[r] * mean[r];
                rstd[r] = rsqrtf(var + 1e-5f);
            }
            #pragma unroll
            for (int n = 0; n < 3; n++) {
                int col = wid * 48 + n * 16 + lr;
                float gg = g1[col], bb = t1[col];
                #pragma unroll
                for (int r = 0; r < 4; r++) {
                    float y = (acc[rg][n][r] - mean[r]) * rstd[r] * gg + bb;
                    yres[rg][n][r] = y;
                    ybf[rg * 16 + lg * 4 + r][col] = (short)f2bu(y);
                }
            }
        }
        __syncthreads();
    }
    // ---- phase B: ffn1 (K=192 from ybf, N=256) + ReLU -> hid ----
    {
        const short* b_base = (const short*)Bt1 + (size_t)(wid * 64 + lr) * 192 + lg * 8;
        f32x4 acc[2][4] = {};
        #pragma unroll
        for (int kk = 0; kk < 6; kk++) {
            short8 af0 = *(const short8*)&ybf[lr][lg * 8 + kk * 32];
            short8 af1 = *(const short8*)&ybf[16 + lr][lg * 8 + kk * 32];
            #pragma unroll
            for (int n = 0; n < 4; n++) {
                short8 bfr = *(const short8*)(b_base + (size_t)n * 16 * 192 + kk * 32);
                acc[0][n] = __builtin_amdgcn_mfma_f32_16x16x32_bf16(af0, bfr, acc[0][n], 0, 0, 0);
                acc[1][n] = __builtin_amdgcn_mfma_f32_16x16x32_bf16(af1, bfr, acc[1][n], 0, 0, 0);
            }
        }
        #pragma unroll
        for (int rg = 0; rg < 2; rg++)
            #pragma unroll
            for (int n = 0; n < 4; n++) {
                int col = wid * 64 + n * 16 + lr;
                float bv = b1[col];
                #pragma unroll
                for (int r = 0; r < 4; r++)
                    hid[rg * 16 + lg * 4 + r][col] = (short)f2bu(fmaxf(acc[rg][n][r] + bv, 0.f));
            }
        __syncthreads();
    }
    // ---- phase C: ffn2 (K=256 from hid, N=192) + resid(yres) + LN2 ----
    {
        const short* b_base = (const short*)Bt2 + (size_t)(wid * 48 + lr) * 256 + lg * 8;
        f32x4 acc[2][3] = {};
        #pragma unroll
        for (int kk = 0; kk < 8; kk++) {
            short8 af0 = *(const short8*)&hid[lr][lg * 8 + kk * 32];
            short8 af1 = *(const short8*)&hid[16 + lr][lg * 8 + kk * 32];
            #pragma unroll
            for (int n = 0; n < 3; n++) {
                short8 bfr = *(const short8*)(b_base + (size_t)n * 16 * 256 + kk * 32);
                acc[0][n] = __builtin_amdgcn_mfma_f32_16x16x32_bf16(af0, bfr, acc[0][n], 0, 0, 0);
                acc[1][n] = __builtin_amdgcn_mfma_f32_16x16x32_bf16(af1, bfr, acc[1][n], 0, 0, 0);
            }
        }
        #pragma unroll
        for (int rg = 0; rg < 2; rg++) {
            float s[4] = {0.f, 0.f, 0.f, 0.f}, q[4] = {0.f, 0.f, 0.f, 0.f};
            #pragma unroll
            for (int n = 0; n < 3; n++) {
                int col = wid * 48 + n * 16 + lr;
                float bv = b2[col];
                #pragma unroll
                for (int r = 0; r < 4; r++) {
                    float v = acc[rg][n][r] + bv + yres[rg][n][r];
                    acc[rg][n][r] = v;
                    s[r] += v; q[r] += v * v;
                }
            }
            #pragma unroll
            for (int r = 0; r < 4; r++) {
                #pragma unroll
                for (int m = 1; m < 16; m <<= 1) {
                    s[r] += __shfl_xor(s[r], m); q[r] += __shfl_xor(q[r], m);
                }
            }
            if (lr == 0) {
                #pragma unroll
                for (int r = 0; r < 4; r++) {
                    ps[wid][rg * 16 + lg * 4 + r] = s[r];
                    pq[wid][rg * 16 + lg * 4 + r] = q[r];
                }
            }
        }
        __syncthreads();    // also guarantees all hid/ybf reads are done
        #pragma unroll
        for (int rg = 0; rg < 2; rg++) {
            float mean[4], rstd[4];
            #pragma unroll
            for (int r = 0; r < 4; r++) {
                int rl = rg * 16 + lg * 4 + r;
                float S = ps[0][rl] + ps[1][rl] + ps[2][rl] + ps[3][rl];
                float Q = pq[0][rl] + pq[1][rl] + pq[2][rl] + pq[3][rl];
                mean[r] = S * (1.f / Dm);
                float var = Q * (1.f / Dm) - mean[r] * mean[r];
                rstd[r] = rsqrtf(var + 1e-5f);
            }
            #pragma unroll
            for (int n = 0; n < 3; n++) {
                int col = wid * 48 + n * 16 + lr;
                float gg = g2[col], bb = t2[col];
                #pragma unroll
                for (int r = 0; r < 4; r++) {
                    int row = row0 + rg * 16 + lg * 4 + r;
                    int rl = rg * 16 + lg * 4 + r;
                    float y = (acc[rg][n][r] - mean[r]) * rstd[r] * gg + bb;
                    OUTp[(size_t)row * Dm + col] = y;
                    if (!LAST) {
                        ybf[rl][col] = (short)f2bu(y);
                        int tp = (row >= LSEQ) ? row - LSEQ : row;
                        hid[rl][col] = (short)f2bu(y + pos[(size_t)tp * Dm + col]);
                    }
                }
            }
        }
    }
    if (LAST) return;
    __syncthreads();
    // ---- phase D1: vp GEMM (y from ybf) -> Vout fp32 ----
    {
        const short* b_base = (const short*)BtV + (size_t)(wid * 48 + lr) * 192 + lg * 8;
        f32x4 acc[2][3] = {};
        #pragma unroll
        for (int kk = 0; kk < 6; kk++) {
            short8 af0 = *(const short8*)&ybf[lr][lg * 8 + kk * 32];
            short8 af1 = *(const short8*)&ybf[16 + lr][lg * 8 + kk * 32];
            #pragma unroll
            for (int n = 0; n < 3; n++) {
                short8 bfr = *(const short8*)(b_base + (size_t)n * 16 * 192 + kk * 32);
                acc[0][n] = __builtin_amdgcn_mfma_f32_16x16x32_bf16(af0, bfr, acc[0][n], 0, 0, 0);
                acc[1][n] = __builtin_amdgcn_mfma_f32_16x16x32_bf16(af1, bfr, acc[1][n], 0, 0, 0);
            }
        }
        #pragma unroll
        for (int rg = 0; rg < 2; rg++)
            #pragma unroll
            for (int n = 0; n < 3; n++) {
                int col = wid * 48 + n * 16 + lr;
                float bv = biasV[col];
                #pragma unroll
                for (int r = 0; r < 4; r++)
                    Vout[(size_t)(row0 + rg * 16 + lg * 4 + r) * Dm + col] = acc[rg][n][r] + bv;
            }
    }
    // ---- phase D2: soaw GEMM (q from hid) -> softmax/loc epilogue ----
    {
        const short* b_base = (const short*)BtS + (size_t)(wid * 48 + lr) * 192 + lg * 8;
        f32x4 acc[2][3] = {};
        #pragma unroll
        for (int kk = 0; kk < 6; kk++) {
            short8 af0 = *(const short8*)&hid[lr][lg * 8 + kk * 32];
            short8 af1 = *(const short8*)&hid[16 + lr][lg * 8 + kk * 32];
            #pragma unroll
            for (int n = 0; n < 3; n++) {
                short8 bfr = *(const short8*)(b_base + (size_t)n * 16 * 192 + kk * 32);
                acc[0][n] = __builtin_amdgcn_mfma_f32_16x16x32_bf16(af0, bfr, acc[0][n], 0, 0, 0);
                acc[1][n] = __builtin_amdgcn_mfma_f32_16x16x32_bf16(af1, bfr, acc[1][n], 0, 0, 0);
            }
        }
        #pragma unroll
        for (int rg = 0; rg < 2; rg++) {
            #pragma unroll
            for (int n = 0; n < 3; n++) {
                int col = wid * 48 + n * 16 + lr;
                float bv = biasS[col];
                if (col >= 128) {
                    #pragma unroll
                    for (int r = 0; r < 4; r++) {
                        float v = acc[rg][n][r] + bv;
                        float m = v;
                        m = fmaxf(m, __shfl_xor(m, 1)); m = fmaxf(m, __shfl_xor(m, 2));
                        m = fmaxf(m, __shfl_xor(m, 4));
                        float e = expf(v - m);
                        float sm = e;
                        sm += __shfl_xor(sm, 1); sm += __shfl_xor(sm, 2); sm += __shfl_xor(sm, 4);
                        AW[(size_t)(row0 + rg * 16 + lg * 4 + r) * 64 + (col - 128)] = e / sm;
                    }
                } else {
                    #pragma unroll
                    for (int r = 0; r < 4; r++) {
                        int row = row0 + rg * 16 + lg * 4 + r;
                        int t = (row >= LSEQ) ? row - LSEQ : row;
                        int rr, cc, Ht, Wt;
                        if (t < N0) { Ht = 96; Wt = 96; rr = t / 96; cc = t % 96; }
                        else        { Ht = 48; Wt = 48; int tl = t - N0; rr = tl / 48; cc = tl % 48; }
                        float refx = (cc + 0.5f) / (float)Wt;
                        float refy = (rr + 0.5f) / (float)Ht;
                        int j = col >> 1;
                        float sc = (j & 4) ? 48.f : 96.f;
                        LOC[(size_t)row * 128 + col] =
                            ((col & 1) ? refy : refx) + (acc[rg][n][r] + bv) / sc;
                    }
                }
            }
        }
    }
}

// -------------------- final [t][d] -> [d][t] tiled transpose ---------------
__global__ void k_outt(const float* __restrict__ out, float* __restrict__ dst,
        int HW, int st) {
    __shared__ float tile[32][33];
    int t0 = blockIdx.x * 32, d0 = blockIdx.y * 32, b = blockIdx.z;
    int tx = threadIdx.x, ty = threadIdx.y;
    #pragma unroll
    for (int k = 0; k < 4; k++) {
        int t = t0 + ty + k * 8;
        tile[ty + k * 8][tx] = out[((size_t)b * LSEQ + st + t) * Dm + d0 + tx];
    }
    __syncthreads();
    #pragma unroll
    for (int k = 0; k < 4; k++) {
        int d = d0 + ty + k * 8;
        dst[((size_t)b * Dm + d) * HW + t0 + tx] = tile[tx][ty + k * 8];
    }
}

extern "C" void kernel_launch(void* const* d_in, const int* in_sizes, int n_in,
                              void* d_out, int out_size, void* d_ws, size_t ws_size,
                              hipStream_t stream) {
    (void)in_sizes; (void)n_in; (void)out_size; (void)ws_size;
    const float* feat0   = (const float*)d_in[0];
    const float* feat1   = (const float*)d_in[1];
    const float* proj_w0 = (const float*)d_in[3];
    const float* proj_b0 = (const float*)d_in[4];
    const float* gn_g0   = (const float*)d_in[5];
    const float* gn_b0   = (const float*)d_in[6];
    const float* proj_w1 = (const float*)d_in[7];
    const float* proj_b1 = (const float*)d_in[8];
    const float* gn_g1   = (const float*)d_in[9];
    const float* gn_b1   = (const float*)d_in[10];
    const float* level_embed = (const float*)d_in[11];
    const float* so_W = (const float*)d_in[12];
    const float* so_b = (const float*)d_in[13];
    const float* aw_W = (const float*)d_in[14];
    const float* aw_b = (const float*)d_in[15];
    const float* vp_W = (const float*)d_in[16];
    const float* vp_b = (const float*)d_in[17];
    const float* op_W = (const float*)d_in[18];
    const float* op_b = (const float*)d_in[19];
    const float* ln1_g = (const float*)d_in[20];
    const float* ln1_b = (const float*)d_in[21];
    const float* l1_W = (const float*)d_in[22];
    const float* l1_b = (const float*)d_in[23];
    const float* l2_W = (const float*)d_in[24];
    const float* l2_b = (const float*)d_in[25];
    const float* ln2_g = (const float*)d_in[26];
    const float* ln2_b = (const float*)d_in[27];

    float* ws   = (float*)d_ws;
    float* OUT  = ws + F_OUT;
    float* PRE  = ws + F_PRE;          // conv-out / GN src; in-loop: V buffer A
    float* POS  = ws + F_POS;
    float* LOC  = ws + F_LOC;
    float* AWp  = ws + F_AW;
    float* V2   = ws + F_V2;           // V buffer B
    __hip_bfloat16* QB  = (__hip_bfloat16*)(ws + F_QB);
    __hip_bfloat16* OB  = (__hip_bfloat16*)(ws + F_OB);
    __hip_bfloat16* AH  = (__hip_bfloat16*)(ws + F_AH);   // ATT
    __hip_bfloat16* WT16 = (__hip_bfloat16*)(ws + F_WT16);
    float* BC   = ws + F_BC;
    float* GNS  = ws + F_GNS;
    // early-phase aliases (consumed before the layer loop)
    __hip_bfloat16* FEATB = (__hip_bfloat16*)(ws + F_LOC);
    __hip_bfloat16* CWB   = (__hip_bfloat16*)(ws + F_AW);
    float* GPART = ws + F_AH;                              // 240*32*2 floats

    k_pos<<<(LSEQ * Dm + 255) / 256, 256, 0, stream>>>(POS, level_embed);
    k_prep<<<(6 * WL_STRIDE + 255) / 256, 256, 0, stream>>>(so_W, aw_W, vp_W, op_W,
        l1_W, l2_W, so_b, aw_b, WT16, BC);
    k_prepc<<<(2 * 36864 + 255) / 256, 256, 0, stream>>>(proj_w0, proj_w1, CWB);
    k_tf<<<dim3(N0 / 32, 6, 2), dim3(32, 8), 0, stream>>>(feat0, FEATB, N0, 0);
    k_tf<<<dim3(N1 / 32, 6, 2), dim3(32, 8), 0, stream>>>(feat1, FEATB, N1, N0);
    for (int b = 0; b < 2; b++) {
        k_gemm<6><<<dim3(N0 / 64, 3), 256, 0, stream>>>(
            FEATB + (size_t)b * LSEQ * Dm, CWB, proj_b0,
            PRE + (size_t)b * LSEQ * Dm, Dm);
        k_gemm<6><<<dim3(N1 / 64, 3), 256, 0, stream>>>(
            FEATB + ((size_t)b * LSEQ + N0) * Dm, CWB + 36864, proj_b1,
            PRE + ((size_t)b * LSEQ + N0) * Dm, Dm);
    }
    k_gnp<<<240, 192, 0, stream>>>(PRE, GPART);
    k_gnf<<<128, 64, 0, stream>>>(GPART, GNS);
    k_gnnorm<<<(Bb * LSEQ * Dm + 255) / 256, 256, 0, stream>>>(PRE, GNS,
        gn_g0, gn_b0, gn_g1, gn_b1, POS, OUT, OB, QB);

    // layer-0 so|aw + vp projections (V -> V2; PRE's conv output already consumed)
    k_soawvp<<<dim3(Mrows / 32, 2), 192, 0, stream>>>(
        QB, OB, WT16 + WL_SOAW, WT16 + WL_VP, BC, vp_b, LOC, AWp, V2);

    float* Vin = V2;
    float* Vout = PRE;
    for (int i = 0; i < 6; i++) {
        const __hip_bfloat16* WL = WT16 + (size_t)i * WL_STRIDE;
        k_sample<<<Mrows / 4, 192, 0, stream>>>(Vin, LOC, AWp, AH);
        if (i < 5) {
            const __hip_bfloat16* WN = WT16 + (size_t)(i + 1) * WL_STRIDE;
            k_tail<false><<<Mrows / 32, 256, 0, stream>>>(
                AH, LOC, AWp,
                WL + WL_OP, op_b + (size_t)i * Dm,
                WL + WL_L1, l1_b + (size_t)i * FFD,
                WL + WL_L2, l2_b + (size_t)i * Dm,
                ln1_g + (size_t)i * Dm, ln1_b + (size_t)i * Dm,
                ln2_g + (size_t)i * Dm, ln2_b + (size_t)i * Dm, POS, OUT,
                WN + WL_SOAW, WN + WL_VP, BC + (i + 1) * 192,
                vp_b + (size_t)(i + 1) * Dm, Vout);
        } else {
            k_tail<true><<<Mrows / 32, 256, 0, stream>>>(
                AH, LOC, AWp,
                WL + WL_OP, op_b + (size_t)i * Dm,
                WL + WL_L1, l1_b + (size_t)i * FFD,
                WL + WL_L2, l2_b + (size_t)i * Dm,
                ln1_g + (size_t)i * Dm, ln1_b + (size_t)i * Dm,
                ln2_g + (size_t)i * Dm, ln2_b + (size_t)i * Dm, POS, OUT,
                nullptr, nullptr, nullptr, nullptr, nullptr);
        }
        float* tswap = Vin; Vin = Vout; Vout = tswap;
    }
    k_outt<<<dim3(N0 / 32, 6, 2), dim3(32, 8), 0, stream>>>(OUT, (float*)d_out, N0, 0);
    k_outt<<<dim3(N1 / 32, 6, 2), dim3(32, 8), 0, stream>>>(OUT,
        (float*)d_out + (size_t)Bb * Dm * N0, N1, N0);
}

// Round 12
// 635.975 us; speedup vs baseline: 1.0146x; 1.0146x over previous
//
#include <hip/hip_runtime.h>
#include <hip/hip_bf16.h>
#include <math.h>

#define Bb 2
#define Dm 192
#define NHh 8
#define HDd 24
#define N0 9216
#define N1 2304
#define LSEQ 11520
#define FFD 256
#define Mrows (Bb*LSEQ)            // 23040

typedef __attribute__((ext_vector_type(8))) short short8;
typedef __attribute__((ext_vector_type(4))) float f32x4;

// ---------------- workspace layout (float offsets) ----------------
#define F_OUT 0                         // fp32 [23040][192]
#define F_PRE (F_OUT + 4423680)         // fp32 conv-out/GN src; in-loop: V fp32
#define F_POS (F_PRE + 4423680)         // fp32 [11520][192]
#define F_LOC (F_POS + 2211840)         // fp32 [23040][64][2]   (early: FEATB bf16)
#define F_AW  (F_LOC + 2949120)         // fp32 [23040][64]      (early: CWB bf16)
#define F_QB  (F_AW + 1474560)          // bf16 [23040][192]  (Q)
#define F_OB  (F_QB + 2211840)          // bf16 [23040][192]
#define F_AH  (F_OB + 2211840)          // bf16 [23040][256]  (ATT; early: GPART)
#define F_WT16 (F_AH + 2949120)         // bf16 weights, 6*208896 elems
#define F_BC  (F_WT16 + 626688)         // fp32 [6][192] concat so|aw bias
#define F_GNS (F_BC + 1152)             // fp32 group-norm stats (128*2)
// end ~ 24.6M floats ~= 99 MB (ws = 256 MiB)

// per-layer WT16 sub-offsets (bf16 elems)
#define WL_STRIDE 208896
#define WL_SOAW 0
#define WL_VP   36864
#define WL_OP   73728
#define WL_L1   110592
#define WL_L2   159744

__device__ inline __hip_bfloat16 f2b(float f) { return __float2bfloat16(f); }
__device__ inline unsigned short f2bu(float f) {
    __hip_bfloat16 h = __float2bfloat16(f);
    return *reinterpret_cast<unsigned short*>(&h);
}

// -------------------- pos embed --------------------
__global__ void k_pos(float* pos, const float* level_embed) {
    int idx = blockIdx.x * 256 + threadIdx.x;
    if (idx >= LSEQ * Dm) return;
    int t = idx / Dm, d = idx % Dm;
    int lvl, row, col, H, W;
    if (t < N0) { lvl = 0; H = 96; W = 96; row = t / 96; col = t % 96; }
    else        { lvl = 1; H = 48; W = 48; int tl = t - N0; row = tl / 48; col = tl % 48; }
    int k = d % 96;
    float v;
    if (d < 96) v = (row + 0.5f) / ((float)H + 1e-6f) * 6.2831853071795864f;
    else        v = (col + 0.5f) / ((float)W + 1e-6f) * 6.2831853071795864f;
    float expo = (float)(k - (k & 1)) / 96.0f;
    float tm = exp2f(expo * 13.287712379549449f);   // 10000^expo
    float p = v / tm;
    float pe = (k & 1) ? cosf(p) : sinf(p);
    pos[idx] = pe + level_embed[lvl * Dm + d];
}

// -------------------- prep: transpose + bf16-convert encoder weights ----
__global__ void k_prep(const float* soW, const float* awW, const float* vpW,
        const float* opW, const float* l1W, const float* l2W,
        const float* sob, const float* awb,
        __hip_bfloat16* WT, float* BC) {
    int idx = blockIdx.x * 256 + threadIdx.x;
    if (idx < 6 * 192) {
        int i = idx / 192, n = idx % 192;
        BC[idx] = (n < 128) ? sob[i * 128 + n] : awb[i * 64 + (n - 128)];
    }
    if (idx >= 6 * WL_STRIDE) return;
    int i = idx / WL_STRIDE; int r = idx % WL_STRIDE;
    float v;
    if (r < 36864)       { int n = r / 192, k = r % 192;
        v = (n < 128) ? soW[((size_t)i * 192 + k) * 128 + n]
                      : awW[((size_t)i * 192 + k) * 64 + (n - 128)]; }
    else if (r < 73728)  { int q = r - 36864;  int n = q / 192, k = q % 192;
        v = vpW[((size_t)i * 192 + k) * 192 + n]; }
    else if (r < 110592) { int q = r - 73728;  int n = q / 192, k = q % 192;
        v = opW[((size_t)i * 192 + k) * 192 + n]; }
    else if (r < 159744) { int q = r - 110592; int n = q / 192, k = q % 192;
        v = l1W[((size_t)i * 192 + k) * 256 + n]; }
    else                 { int q = r - 159744; int n = q / 256, k = q % 256;
        v = l2W[((size_t)i * 256 + k) * 192 + n]; }
    WT[idx] = f2b(v);
}

// conv weights: proj_w is [o][c] which is exactly Bt[N][K] — just convert
__global__ void k_prepc(const float* w0, const float* w1, __hip_bfloat16* cwb) {
    int idx = blockIdx.x * 256 + threadIdx.x;
    if (idx >= 2 * 36864) return;
    const float* w = (idx < 36864) ? w0 : w1;
    int r = idx % 36864;
    cwb[idx] = f2b(w[r]);
}

// -------------------- feature transpose [b][c][t] -> bf16 [t][c] ----------
__global__ void k_tf(const float* feat, __hip_bfloat16* out, int HW, int st) {
    __shared__ float tile[32][33];
    int t0 = blockIdx.x * 32, c0 = blockIdx.y * 32, b = blockIdx.z;
    int tx = threadIdx.x, ty = threadIdx.y;
    #pragma unroll
    for (int k = 0; k < 4; k++) {
        int c = c0 + ty + k * 8;
        tile[ty + k * 8][tx] = feat[((size_t)b * Dm + c) * HW + t0 + tx];
    }
    __syncthreads();
    #pragma unroll
    for (int k = 0; k < 4; k++) {
        int t = t0 + ty + k * 8;
        out[((size_t)b * LSEQ + st + t) * Dm + c0 + tx] = f2b(tile[tx][ty + k * 8]);
    }
}

// -------------------- GN partial sums (coalesced) --------------------
__global__ __launch_bounds__(192) void k_gnp(const float* __restrict__ pre,
        float* __restrict__ part) {
    int bid = blockIdx.x;                 // 0..239
    int b = bid / 120; int r = bid % 120;
    int l = (r >= 96) ? 1 : 0; int ch = l ? (r - 96) : r;
    int start = b * LSEQ + (l ? N0 : 0) + ch * 96;
    int d = threadIdx.x;
    float s = 0.f, sq = 0.f;
    for (int t = 0; t < 96; t++) {
        float x = pre[(size_t)(start + t) * Dm + d];
        s += x; sq += x * x;
    }
    __shared__ float ls[192], lq[192];
    ls[d] = s; lq[d] = sq;
    __syncthreads();
    if (d < 32) {
        float a = 0.f, b2 = 0.f;
        #pragma unroll
        for (int j = 0; j < 6; j++) { a += ls[d * 6 + j]; b2 += lq[d * 6 + j]; }
        part[((size_t)bid * 32 + d) * 2]     = a;
        part[((size_t)bid * 32 + d) * 2 + 1] = b2;
    }
}

__global__ void k_gnf(const float* __restrict__ part, float* __restrict__ gns) {
    int bid = blockIdx.x;                 // (b,l,g): 128
    int b = bid >> 6; int l = (bid >> 5) & 1; int g = bid & 31;
    int nch = l ? 24 : 96;
    int base = b * 120 + (l ? 96 : 0);
    int tid = threadIdx.x;
    float s = 0.f, q = 0.f;
    for (int c = tid; c < nch; c += 64) {
        s += part[((size_t)(base + c) * 32 + g) * 2];
        q += part[((size_t)(base + c) * 32 + g) * 2 + 1];
    }
    for (int m = 1; m < 64; m <<= 1) { s += __shfl_xor(s, m, 64); q += __shfl_xor(q, m, 64); }
    if (tid == 0) {
        float total = (float)((l ? N1 : N0) * 6);
        float mean = s / total;
        float var = q / total - mean * mean;
        gns[bid * 2] = mean;
        gns[bid * 2 + 1] = rsqrtf(var + 1e-5f);
    }
}

// -------------------- group norm apply: OUT f32 + O bf16 + Q bf16 ----------
__global__ void k_gnnorm(const float* srcp, const float* gns,
        const float* g0, const float* b0, const float* g1, const float* b1,
        const float* pos, float* out, __hip_bfloat16* ob, __hip_bfloat16* qb) {
    int idx = blockIdx.x * 256 + threadIdx.x;
    if (idx >= Bb * LSEQ * Dm) return;
    int d = idx % Dm;
    int t = (idx / Dm) % LSEQ;
    int l = (t < N0) ? 0 : 1;
    int g = d / 6;
    int b = idx / (Dm * LSEQ);
    int sid = ((b * 2 + l) * 32 + g) * 2;
    float mean = gns[sid], rstd = gns[sid + 1];
    float gg = l ? g1[d] : g0[d];
    float bbv = l ? b1[d] : b0[d];
    float v = (srcp[idx] - mean) * rstd * gg + bbv;
    out[idx] = v;
    ob[idx] = f2b(v);
    qb[idx] = f2b(v + pos[idx - (size_t)b * LSEQ * Dm]);
}

// -------------------- bf16 MFMA GEMM (conv path) --------------------------
template<int KSTEPS>
__global__ __launch_bounds__(256) void k_gemm(
        const __hip_bfloat16* __restrict__ A,
        const __hip_bfloat16* __restrict__ Bt,
        const float* __restrict__ bias,
        float* __restrict__ Cf, int N) {
    constexpr int K = KSTEPS * 32;
    int wid = threadIdx.x >> 6, lane = threadIdx.x & 63;
    int lg = lane >> 4, lr = lane & 15;
    int row0 = blockIdx.x * 64 + wid * 16;
    int col0 = blockIdx.y * 64;
    const short* a_base = (const short*)A + (size_t)(row0 + lr) * K + lg * 8;
    const short* b_base = (const short*)Bt + (size_t)(col0 + lr) * K + lg * 8;
    f32x4 acc[4] = {};
    #pragma unroll
    for (int kk = 0; kk < KSTEPS; kk++) {
        short8 af = *(const short8*)(a_base + kk * 32);
        #pragma unroll
        for (int n = 0; n < 4; n++) {
            short8 bfr = *(const short8*)(b_base + (size_t)n * 16 * K + kk * 32);
            acc[n] = __builtin_amdgcn_mfma_f32_16x16x32_bf16(af, bfr, acc[n], 0, 0, 0);
        }
    }
    #pragma unroll
    for (int n = 0; n < 4; n++) {
        int col = col0 + n * 16 + lr;
        float bv = bias[col];
        #pragma unroll
        for (int r = 0; r < 4; r++) {
            int row = row0 + lg * 4 + r;
            Cf[(size_t)row * N + col] = acc[n][r] + bv;
        }
    }
}

// ------------- merged soaw + value-proj dispatch (BM=32, regs-held B) -----
// grid (Mrows/32, 2); 192 thr = 3 waves, wave w -> cols w*64..w*64+63
// role y==0: soaw from QB (softmax+loc epilogue); y==1: vp from OB -> VF fp32
__global__ __launch_bounds__(192) void k_soawvp(
        const __hip_bfloat16* __restrict__ QB,
        const __hip_bfloat16* __restrict__ OB,
        const __hip_bfloat16* __restrict__ BtS,
        const __hip_bfloat16* __restrict__ BtV,
        const float* __restrict__ biasS,
        const float* __restrict__ biasV,
        float* __restrict__ LOC, float* __restrict__ AW,
        float* __restrict__ VF) {
    constexpr int K = 192;
    int wid = threadIdx.x >> 6, lane = threadIdx.x & 63;
    int lg = lane >> 4, lr = lane & 15;
    int row0 = blockIdx.x * 32;
    int col0 = wid * 64;
    int role = blockIdx.y;
    const short* A  = (const short*)(role ? OB : QB);
    const short* Bt = (const short*)(role ? BtV : BtS);
    const float* bias = role ? biasV : biasS;
    short8 bw[24];
    {
        const short* b_base = Bt + (size_t)(col0 + lr) * K + lg * 8;
        #pragma unroll
        for (int n = 0; n < 4; n++)
            #pragma unroll
            for (int kk = 0; kk < 6; kk++)
                bw[n * 6 + kk] = *(const short8*)(b_base + (size_t)n * 16 * K + kk * 32);
    }
    #pragma unroll
    for (int rg = 0; rg < 2; rg++) {
        const short* a_base = A + (size_t)(row0 + rg * 16 + lr) * K + lg * 8;
        f32x4 acc[4] = {};
        __builtin_amdgcn_s_setprio(1);
        #pragma unroll
        for (int kk = 0; kk < 6; kk++) {
            short8 af = *(const short8*)(a_base + kk * 32);
            #pragma unroll
            for (int n = 0; n < 4; n++)
                acc[n] = __builtin_amdgcn_mfma_f32_16x16x32_bf16(af, bw[n * 6 + kk], acc[n], 0, 0, 0);
        }
        __builtin_amdgcn_s_setprio(0);
        #pragma unroll
        for (int n = 0; n < 4; n++) {
            float bv = bias[col0 + n * 16 + lr];
            #pragma unroll
            for (int r = 0; r < 4; r++) acc[n][r] += bv;
        }
        int rbase = row0 + rg * 16;
        if (role) {
            #pragma unroll
            for (int n = 0; n < 4; n++) {
                int col = col0 + n * 16 + lr;
                #pragma unroll
                for (int r = 0; r < 4; r++)
                    VF[(size_t)(rbase + lg * 4 + r) * Dm + col] = acc[n][r];
            }
        } else if (wid == 2) {
            // attn-weight softmax: head = 8 consecutive cols within this wave
            #pragma unroll
            for (int n = 0; n < 4; n++) {
                #pragma unroll
                for (int r = 0; r < 4; r++) {
                    float v = acc[n][r];
                    float m = v;
                    m = fmaxf(m, __shfl_xor(m, 1)); m = fmaxf(m, __shfl_xor(m, 2));
                    m = fmaxf(m, __shfl_xor(m, 4));
                    float e = expf(v - m);
                    float sm = e;
                    sm += __shfl_xor(sm, 1); sm += __shfl_xor(sm, 2); sm += __shfl_xor(sm, 4);
                    AW[(size_t)(rbase + lg * 4 + r) * 64 + n * 16 + lr] = e / sm;
                }
            }
        } else {
            // sampling locations (cols 0..127)
            #pragma unroll
            for (int r = 0; r < 4; r++) {
                int row = rbase + lg * 4 + r;
                int t = (row >= LSEQ) ? row - LSEQ : row;
                int rr, cc, Ht, Wt;
                if (t < N0) { Ht = 96; Wt = 96; rr = t / 96; cc = t % 96; }
                else        { Ht = 48; Wt = 48; int tl = t - N0; rr = tl / 48; cc = tl % 48; }
                float refx = (cc + 0.5f) / (float)Wt;
                float refy = (rr + 0.5f) / (float)Ht;
                #pragma unroll
                for (int n = 0; n < 4; n++) {
                    int col = col0 + n * 16 + lr;
                    int j = col >> 1, comp = col & 1;
                    float sc = (j & 4) ? 48.f : 96.f;
                    LOC[(size_t)row * 128 + col] = (comp ? refy : refx) + acc[n][r] / sc;
                }
            }
        }
    }
}

// ------------- fused tail: op GEMM + LN1 + FFN1 + FFN2 + LN2 + Q ----------
// BM=32, shared-B interleave: each streamed B-frag feeds 2 row-groups.
// grid (Mrows/32); 256 thr = 4 waves. op/ffn2: wave cols w*48; ffn1: w*64.
// LN1 output kept in registers for the phase-C residual (same lane mapping).
__global__ __launch_bounds__(256) void k_tail(
        const __hip_bfloat16* __restrict__ ATT,
        const __hip_bfloat16* __restrict__ BtOp, const float* __restrict__ bOp,
        const __hip_bfloat16* __restrict__ Bt1, const float* __restrict__ b1,
        const __hip_bfloat16* __restrict__ Bt2, const float* __restrict__ b2,
        const float* __restrict__ g1, const float* __restrict__ t1,
        const float* __restrict__ g2, const float* __restrict__ t2,
        const float* __restrict__ pos,
        float* __restrict__ OUTp, __hip_bfloat16* __restrict__ ob,
        __hip_bfloat16* __restrict__ qb) {
    __shared__ __align__(16) short ybf[32][200];
    __shared__ __align__(16) short hid[32][264];
    __shared__ float ps[4][32], pq[4][32];
    int tid = threadIdx.x;
    int wid = tid >> 6, lane = tid & 63, lg = lane >> 4, lr = lane & 15;
    int row0 = blockIdx.x * 32;
    float yres[2][3][4];
    // ---- phase A: op GEMM (K=192, N=192) + bias + residual + LN1 ----
    {
        float resid[2][3][4];
        #pragma unroll
        for (int rg = 0; rg < 2; rg++)
            #pragma unroll
            for (int n = 0; n < 3; n++) {
                int col = wid * 48 + n * 16 + lr;
                #pragma unroll
                for (int r = 0; r < 4; r++)
                    resid[rg][n][r] = OUTp[(size_t)(row0 + rg * 16 + lg * 4 + r) * Dm + col];
            }
        const short* a0 = (const short*)ATT + (size_t)(row0 + lr) * 192 + lg * 8;
        const short* a1 = (const short*)ATT + (size_t)(row0 + 16 + lr) * 192 + lg * 8;
        const short* b_base = (const short*)BtOp + (size_t)(wid * 48 + lr) * 192 + lg * 8;
        f32x4 acc[2][3] = {};
        __builtin_amdgcn_s_setprio(1);
        #pragma unroll
        for (int kk = 0; kk < 6; kk++) {
            short8 af0 = *(const short8*)(a0 + kk * 32);
            short8 af1 = *(const short8*)(a1 + kk * 32);
            #pragma unroll
            for (int n = 0; n < 3; n++) {
                short8 bfr = *(const short8*)(b_base + (size_t)n * 16 * 192 + kk * 32);
                acc[0][n] = __builtin_amdgcn_mfma_f32_16x16x32_bf16(af0, bfr, acc[0][n], 0, 0, 0);
                acc[1][n] = __builtin_amdgcn_mfma_f32_16x16x32_bf16(af1, bfr, acc[1][n], 0, 0, 0);
            }
        }
        __builtin_amdgcn_s_setprio(0);
        #pragma unroll
        for (int rg = 0; rg < 2; rg++) {
            float s[4] = {0.f, 0.f, 0.f, 0.f}, q[4] = {0.f, 0.f, 0.f, 0.f};
            #pragma unroll
            for (int n = 0; n < 3; n++) {
                int col = wid * 48 + n * 16 + lr;
                float bv = bOp[col];
                #pragma unroll
                for (int r = 0; r < 4; r++) {
                    float v = acc[rg][n][r] + bv + resid[rg][n][r];
                    acc[rg][n][r] = v;
                    s[r] += v; q[r] += v * v;
                }
            }
            #pragma unroll
            for (int r = 0; r < 4; r++) {
                #pragma unroll
                for (int m = 1; m < 16; m <<= 1) {
                    s[r] += __shfl_xor(s[r], m); q[r] += __shfl_xor(q[r], m);
                }
            }
            if (lr == 0) {
                #pragma unroll
                for (int r = 0; r < 4; r++) {
                    ps[wid][rg * 16 + lg * 4 + r] = s[r];
                    pq[wid][rg * 16 + lg * 4 + r] = q[r];
                }
            }
        }
        __syncthreads();
        #pragma unroll
        for (int rg = 0; rg < 2; rg++) {
            float mean[4], rstd[4];
            #pragma unroll
            for (int r = 0; r < 4; r++) {
                int rl = rg * 16 + lg * 4 + r;
                float S = ps[0][rl] + ps[1][rl] + ps[2][rl] + ps[3][rl];
                float Q = pq[0][rl] + pq[1][rl] + pq[2][rl] + pq[3][rl];
                mean[r] = S * (1.f / Dm);
                float var = Q * (1.f / Dm) - mean[r] * mean[r];
                rstd[r] = rsqrtf(var + 1e-5f);
            }
            #pragma unroll
            for (int n = 0; n < 3; n++) {
                int col = wid * 48 + n * 16 + lr;
                float gg = g1[col], bb = t1[col];
                #pragma unroll
                for (int r = 0; r < 4; r++) {
                    float y = (acc[rg][n][r] - mean[r]) * rstd[r] * gg + bb;
                    yres[rg][n][r] = y;
                    ybf[rg * 16 + lg * 4 + r][col] = (short)f2bu(y);
                }
            }
        }
        __syncthreads();
    }
    // ---- phase B: ffn1 (K=192 from ybf, N=256) + ReLU -> hid ----
    {
        const short* b_base = (const short*)Bt1 + (size_t)(wid * 64 + lr) * 192 + lg * 8;
        f32x4 acc[2][4] = {};
        __builtin_amdgcn_s_setprio(1);
        #pragma unroll
        for (int kk = 0; kk < 6; kk++) {
            short8 af0 = *(const short8*)&ybf[lr][lg * 8 + kk * 32];
            short8 af1 = *(const short8*)&ybf[16 + lr][lg * 8 + kk * 32];
            #pragma unroll
            for (int n = 0; n < 4; n++) {
                short8 bfr = *(const short8*)(b_base + (size_t)n * 16 * 192 + kk * 32);
                acc[0][n] = __builtin_amdgcn_mfma_f32_16x16x32_bf16(af0, bfr, acc[0][n], 0, 0, 0);
                acc[1][n] = __builtin_amdgcn_mfma_f32_16x16x32_bf16(af1, bfr, acc[1][n], 0, 0, 0);
            }
        }
        __builtin_amdgcn_s_setprio(0);
        #pragma unroll
        for (int rg = 0; rg < 2; rg++)
            #pragma unroll
            for (int n = 0; n < 4; n++) {
                int col = wid * 64 + n * 16 + lr;
                float bv = b1[col];
                #pragma unroll
                for (int r = 0; r < 4; r++)
                    hid[rg * 16 + lg * 4 + r][col] = (short)f2bu(fmaxf(acc[rg][n][r] + bv, 0.f));
            }
        __syncthreads();
    }
    // ---- phase C: ffn2 (K=256 from hid, N=192) + resid(yres) + LN2 + out --
    {
        const short* b_base = (const short*)Bt2 + (size_t)(wid * 48 + lr) * 256 + lg * 8;
        f32x4 acc[2][3] = {};
        __builtin_amdgcn_s_setprio(1);
        #pragma unroll
        for (int kk = 0; kk < 8; kk++) {
            short8 af0 = *(const short8*)&hid[lr][lg * 8 + kk * 32];
            short8 af1 = *(const short8*)&hid[16 + lr][lg * 8 + kk * 32];
            #pragma unroll
            for (int n = 0; n < 3; n++) {
                short8 bfr = *(const short8*)(b_base + (size_t)n * 16 * 256 + kk * 32);
                acc[0][n] = __builtin_amdgcn_mfma_f32_16x16x32_bf16(af0, bfr, acc[0][n], 0, 0, 0);
                acc[1][n] = __builtin_amdgcn_mfma_f32_16x16x32_bf16(af1, bfr, acc[1][n], 0, 0, 0);
            }
        }
        __builtin_amdgcn_s_setprio(0);
        #pragma unroll
        for (int rg = 0; rg < 2; rg++) {
            float s[4] = {0.f, 0.f, 0.f, 0.f}, q[4] = {0.f, 0.f, 0.f, 0.f};
            #pragma unroll
            for (int n = 0; n < 3; n++) {
                int col = wid * 48 + n * 16 + lr;
                float bv = b2[col];
                #pragma unroll
                for (int r = 0; r < 4; r++) {
                    float v = acc[rg][n][r] + bv + yres[rg][n][r];
                    acc[rg][n][r] = v;
                    s[r] += v; q[r] += v * v;
                }
            }
            #pragma unroll
            for (int r = 0; r < 4; r++) {
                #pragma unroll
                for (int m = 1; m < 16; m <<= 1) {
                    s[r] += __shfl_xor(s[r], m); q[r] += __shfl_xor(q[r], m);
                }
            }
            if (lr == 0) {
                #pragma unroll
                for (int r = 0; r < 4; r++) {
                    ps[wid][rg * 16 + lg * 4 + r] = s[r];
                    pq[wid][rg * 16 + lg * 4 + r] = q[r];
                }
            }
        }
        __syncthreads();
        #pragma unroll
        for (int rg = 0; rg < 2; rg++) {
            float mean[4], rstd[4];
            #pragma unroll
            for (int r = 0; r < 4; r++) {
                int rl = rg * 16 + lg * 4 + r;
                float S = ps[0][rl] + ps[1][rl] + ps[2][rl] + ps[3][rl];
                float Q = pq[0][rl] + pq[1][rl] + pq[2][rl] + pq[3][rl];
                mean[r] = S * (1.f / Dm);
                float var = Q * (1.f / Dm) - mean[r] * mean[r];
                rstd[r] = rsqrtf(var + 1e-5f);
            }
            #pragma unroll
            for (int n = 0; n < 3; n++) {
                int col = wid * 48 + n * 16 + lr;
                float gg = g2[col], bb = t2[col];
                #pragma unroll
                for (int r = 0; r < 4; r++) {
                    int row = row0 + rg * 16 + lg * 4 + r;
                    size_t o = (size_t)row * Dm + col;
                    float y = (acc[rg][n][r] - mean[r]) * rstd[r] * gg + bb;
                    OUTp[o] = y;
                    ob[o] = f2b(y);
                    int tp = (row >= LSEQ) ? row - LSEQ : row;
                    qb[o] = f2b(y + pos[(size_t)tp * Dm + col]);
                }
            }
        }
    }
}

// -------------------- deformable sampling (fp32 V, vectorized) -------------
// block = 192 thr = 4 tokens x 48 lanes (8 heads x 6 d-quads)
__global__ __launch_bounds__(192) void k_sample(const float* __restrict__ V,
        const float* __restrict__ LOC, const float* __restrict__ AW,
        __hip_bfloat16* __restrict__ ATT) {
    __shared__ float aw_s[4][64];
    __shared__ float loc_s[4][128];
    int tid = threadIdx.x;
    int tg0 = blockIdx.x * 4;
    for (int idx = tid; idx < 256; idx += 192)
        aw_s[idx >> 6][idx & 63] = AW[(size_t)tg0 * 64 + idx];
    for (int idx = tid; idx < 512; idx += 192)
        loc_s[idx >> 7][idx & 127] = LOC[(size_t)tg0 * 128 + idx];
    __syncthreads();
    int tt = tid / 48, lane = tid - tt * 48;
    int h = lane / 6, dq = lane - h * 6;
    int tg = tg0 + tt;
    int b = (tg >= LSEQ) ? 1 : 0;
    const float* vb = V + (size_t)b * LSEQ * Dm + h * HDd + dq * 4;
    float a0 = 0.f, a1 = 0.f, a2 = 0.f, a3 = 0.f;
    #pragma unroll
    for (int lp = 0; lp < 8; lp++) {
        int l = lp >> 2;
        int Wl = l ? 48 : 96, Hl = l ? 48 : 96, st = l ? N0 : 0;
        float a  = aw_s[tt][h * 8 + lp];
        float lx = loc_s[tt][(h * 8 + lp) * 2];
        float ly = loc_s[tt][(h * 8 + lp) * 2 + 1];
        float x = lx * (float)Wl - 0.5f, y = ly * (float)Hl - 0.5f;
        float x0f = floorf(x), y0f = floorf(y);
        float wx = x - x0f, wy = y - y0f;
        int x0 = (int)x0f, y0 = (int)y0f;
        #pragma unroll
        for (int cy = 0; cy < 2; cy++) {
            int yi = y0 + cy;
            float wyv = cy ? wy : 1.f - wy;
            bool vy = (yi >= 0) && (yi < Hl);
            int yc = min(max(yi, 0), Hl - 1);
            #pragma unroll
            for (int cx = 0; cx < 2; cx++) {
                int xi = x0 + cx;
                float wv = (cx ? wx : 1.f - wx) * wyv;
                bool ok = vy && (xi >= 0) && (xi < Wl);
                int xc = min(max(xi, 0), Wl - 1);
                float cw = ok ? a * wv : 0.f;
                float4 g4 = *(const float4*)(vb + (size_t)(st + yc * Wl + xc) * Dm);
                a0 += cw * g4.x; a1 += cw * g4.y;
                a2 += cw * g4.z; a3 += cw * g4.w;
            }
        }
    }
    ushort4 o4;
    o4.x = f2bu(a0); o4.y = f2bu(a1); o4.z = f2bu(a2); o4.w = f2bu(a3);
    *(ushort4*)((unsigned short*)ATT + (size_t)tg * Dm + h * HDd + dq * 4) = o4;
}

// -------------------- final [t][d] -> [d][t] tiled transpose ---------------
__global__ void k_outt(const float* __restrict__ out, float* __restrict__ dst,
        int HW, int st) {
    __shared__ float tile[32][33];
    int t0 = blockIdx.x * 32, d0 = blockIdx.y * 32, b = blockIdx.z;
    int tx = threadIdx.x, ty = threadIdx.y;
    #pragma unroll
    for (int k = 0; k < 4; k++) {
        int t = t0 + ty + k * 8;
        tile[ty + k * 8][tx] = out[((size_t)b * LSEQ + st + t) * Dm + d0 + tx];
    }
    __syncthreads();
    #pragma unroll
    for (int k = 0; k < 4; k++) {
        int d = d0 + ty + k * 8;
        dst[((size_t)b * Dm + d) * HW + t0 + tx] = tile[tx][ty + k * 8];
    }
}

extern "C" void kernel_launch(void* const* d_in, const int* in_sizes, int n_in,
                              void* d_out, int out_size, void* d_ws, size_t ws_size,
                              hipStream_t stream) {
    (void)in_sizes; (void)n_in; (void)out_size; (void)ws_size;
    const float* feat0   = (const float*)d_in[0];
    const float* feat1   = (const float*)d_in[1];
    const float* proj_w0 = (const float*)d_in[3];
    const float* proj_b0 = (const float*)d_in[4];
    const float* gn_g0   = (const float*)d_in[5];
    const float* gn_b0   = (const float*)d_in[6];
    const float* proj_w1 = (const float*)d_in[7];
    const float* proj_b1 = (const float*)d_in[8];
    const float* gn_g1   = (const float*)d_in[9];
    const float* gn_b1   = (const float*)d_in[10];
    const float* level_embed = (const float*)d_in[11];
    const float* so_W = (const float*)d_in[12];
    const float* so_b = (const float*)d_in[13];
    const float* aw_W = (const float*)d_in[14];
    const float* aw_b = (const float*)d_in[15];
    const float* vp_W = (const float*)d_in[16];
    const float* vp_b = (const float*)d_in[17];
    const float* op_W = (const float*)d_in[18];
    const float* op_b = (const float*)d_in[19];
    const float* ln1_g = (const float*)d_in[20];
    const float* ln1_b = (const float*)d_in[21];
    const float* l1_W = (const float*)d_in[22];
    const float* l1_b = (const float*)d_in[23];
    const float* l2_W = (const float*)d_in[24];
    const float* l2_b = (const float*)d_in[25];
    const float* ln2_g = (const float*)d_in[26];
    const float* ln2_b = (const float*)d_in[27];

    float* ws   = (float*)d_ws;
    float* OUT  = ws + F_OUT;
    float* PRE  = ws + F_PRE;          // conv-out / GN src; in-loop: V fp32
    float* POS  = ws + F_POS;
    float* LOC  = ws + F_LOC;
    float* AWp  = ws + F_AW;
    __hip_bfloat16* QB  = (__hip_bfloat16*)(ws + F_QB);
    __hip_bfloat16* OB  = (__hip_bfloat16*)(ws + F_OB);
    __hip_bfloat16* AH  = (__hip_bfloat16*)(ws + F_AH);   // ATT
    __hip_bfloat16* WT16 = (__hip_bfloat16*)(ws + F_WT16);
    float* BC   = ws + F_BC;
    float* GNS  = ws + F_GNS;
    // early-phase aliases (consumed before the layer loop)
    __hip_bfloat16* FEATB = (__hip_bfloat16*)(ws + F_LOC);
    __hip_bfloat16* CWB   = (__hip_bfloat16*)(ws + F_AW);
    float* GPART = ws + F_AH;                              // 240*32*2 floats

    k_pos<<<(LSEQ * Dm + 255) / 256, 256, 0, stream>>>(POS, level_embed);
    k_prep<<<(6 * WL_STRIDE + 255) / 256, 256, 0, stream>>>(so_W, aw_W, vp_W, op_W,
        l1_W, l2_W, so_b, aw_b, WT16, BC);
    k_prepc<<<(2 * 36864 + 255) / 256, 256, 0, stream>>>(proj_w0, proj_w1, CWB);
    k_tf<<<dim3(N0 / 32, 6, 2), dim3(32, 8), 0, stream>>>(feat0, FEATB, N0, 0);
    k_tf<<<dim3(N1 / 32, 6, 2), dim3(32, 8), 0, stream>>>(feat1, FEATB, N1, N0);
    for (int b = 0; b < 2; b++) {
        k_gemm<6><<<dim3(N0 / 64, 3), 256, 0, stream>>>(
            FEATB + (size_t)b * LSEQ * Dm, CWB, proj_b0,
            PRE + (size_t)b * LSEQ * Dm, Dm);
        k_gemm<6><<<dim3(N1 / 64, 3), 256, 0, stream>>>(
            FEATB + ((size_t)b * LSEQ + N0) * Dm, CWB + 36864, proj_b1,
            PRE + ((size_t)b * LSEQ + N0) * Dm, Dm);
    }
    k_gnp<<<240, 192, 0, stream>>>(PRE, GPART);
    k_gnf<<<128, 64, 0, stream>>>(GPART, GNS);
    k_gnnorm<<<(Bb * LSEQ * Dm + 255) / 256, 256, 0, stream>>>(PRE, GNS,
        gn_g0, gn_b0, gn_g1, gn_b1, POS, OUT, OB, QB);

    for (int i = 0; i < 6; i++) {
        const __hip_bfloat16* WL = WT16 + (size_t)i * WL_STRIDE;
        k_soawvp<<<dim3(Mrows / 32, 2), 192, 0, stream>>>(
            QB, OB, WL + WL_SOAW, WL + WL_VP, BC + i * 192,
            vp_b + (size_t)i * Dm, LOC, AWp, PRE);
        k_sample<<<Mrows / 4, 192, 0, stream>>>(PRE, LOC, AWp, AH);
        k_tail<<<Mrows / 32, 256, 0, stream>>>(
            AH, WL + WL_OP, op_b + (size_t)i * Dm,
            WL + WL_L1, l1_b + (size_t)i * FFD,
            WL + WL_L2, l2_b + (size_t)i * Dm,
            ln1_g + (size_t)i * Dm, ln1_b + (size_t)i * Dm,
            ln2_g + (size_t)i * Dm, ln2_b + (size_t)i * Dm, POS,
            OUT, OB, QB);
    }
    k_outt<<<dim3(N0 / 32, 6, 2), dim3(32, 8), 0, stream>>>(OUT, (float*)d_out, N0, 0);
    k_outt<<<dim3(N1 / 32, 6, 2), dim3(32, 8), 0, stream>>>(OUT,
        (float*)d_out + (size_t)Bb * Dm * N0, N1, N0);
}

// Round 13
// 619.644 us; speedup vs baseline: 1.0414x; 1.0264x over previous
//
#include <hip/hip_runtime.h>
#include <hip/hip_bf16.h>
#include <math.h>

#define Bb 2
#define Dm 192
#define NHh 8
#define HDd 24
#define N0 9216
#define N1 2304
#define LSEQ 11520
#define FFD 256
#define Mrows (Bb*LSEQ)            // 23040

typedef __attribute__((ext_vector_type(8))) short short8;
typedef __attribute__((ext_vector_type(4))) float f32x4;

// ---------------- workspace layout (float offsets) ----------------
#define F_OUT 0                         // fp32 [23040][192]
#define F_PRE (F_OUT + 4423680)         // fp32 conv-out/GN src; in-loop: V fp32
#define F_POS (F_PRE + 4423680)         // fp32 [11520][192]
#define F_LOC (F_POS + 2211840)         // fp32 [23040][64][2]   (early: FEATB bf16)
#define F_AW  (F_LOC + 2949120)         // fp32 [23040][64]      (early: CWB bf16)
#define F_QB  (F_AW + 1474560)          // bf16 [23040][192]  (Q)
#define F_OB  (F_QB + 2211840)          // bf16 [23040][192]
#define F_AH  (F_OB + 2211840)          // bf16 [23040][256]  (ATT; early: GPART)
#define F_WT16 (F_AH + 2949120)         // bf16 weights, 6*208896 elems
#define F_BC  (F_WT16 + 626688)         // fp32 [6][192] concat so|aw bias
#define F_GNS (F_BC + 1152)             // fp32 group-norm stats (128*2)
// end ~ 24.6M floats ~= 99 MB (ws = 256 MiB)

// per-layer WT16 sub-offsets (bf16 elems)
#define WL_STRIDE 208896
#define WL_SOAW 0
#define WL_VP   36864
#define WL_OP   73728
#define WL_L1   110592
#define WL_L2   159744

__device__ inline __hip_bfloat16 f2b(float f) { return __float2bfloat16(f); }
__device__ inline unsigned short f2bu(float f) {
    __hip_bfloat16 h = __float2bfloat16(f);
    return *reinterpret_cast<unsigned short*>(&h);
}

// -------------------- pos embed --------------------
__global__ void k_pos(float* pos, const float* level_embed) {
    int idx = blockIdx.x * 256 + threadIdx.x;
    if (idx >= LSEQ * Dm) return;
    int t = idx / Dm, d = idx % Dm;
    int lvl, row, col, H, W;
    if (t < N0) { lvl = 0; H = 96; W = 96; row = t / 96; col = t % 96; }
    else        { lvl = 1; H = 48; W = 48; int tl = t - N0; row = tl / 48; col = tl % 48; }
    int k = d % 96;
    float v;
    if (d < 96) v = (row + 0.5f) / ((float)H + 1e-6f) * 6.2831853071795864f;
    else        v = (col + 0.5f) / ((float)W + 1e-6f) * 6.2831853071795864f;
    float expo = (float)(k - (k & 1)) / 96.0f;
    float tm = exp2f(expo * 13.287712379549449f);   // 10000^expo
    float p = v / tm;
    float pe = (k & 1) ? cosf(p) : sinf(p);
    pos[idx] = pe + level_embed[lvl * Dm + d];
}

// -------------------- prep: transpose + bf16-convert encoder weights ----
__global__ void k_prep(const float* soW, const float* awW, const float* vpW,
        const float* opW, const float* l1W, const float* l2W,
        const float* sob, const float* awb,
        __hip_bfloat16* WT, float* BC) {
    int idx = blockIdx.x * 256 + threadIdx.x;
    if (idx < 6 * 192) {
        int i = idx / 192, n = idx % 192;
        BC[idx] = (n < 128) ? sob[i * 128 + n] : awb[i * 64 + (n - 128)];
    }
    if (idx >= 6 * WL_STRIDE) return;
    int i = idx / WL_STRIDE; int r = idx % WL_STRIDE;
    float v;
    if (r < 36864)       { int n = r / 192, k = r % 192;
        v = (n < 128) ? soW[((size_t)i * 192 + k) * 128 + n]
                      : awW[((size_t)i * 192 + k) * 64 + (n - 128)]; }
    else if (r < 73728)  { int q = r - 36864;  int n = q / 192, k = q % 192;
        v = vpW[((size_t)i * 192 + k) * 192 + n]; }
    else if (r < 110592) { int q = r - 73728;  int n = q / 192, k = q % 192;
        v = opW[((size_t)i * 192 + k) * 192 + n]; }
    else if (r < 159744) { int q = r - 110592; int n = q / 192, k = q % 192;
        v = l1W[((size_t)i * 192 + k) * 256 + n]; }
    else                 { int q = r - 159744; int n = q / 256, k = q % 256;
        v = l2W[((size_t)i * 256 + k) * 192 + n]; }
    WT[idx] = f2b(v);
}

// conv weights: proj_w is [o][c] which is exactly Bt[N][K] — just convert
__global__ void k_prepc(const float* w0, const float* w1, __hip_bfloat16* cwb) {
    int idx = blockIdx.x * 256 + threadIdx.x;
    if (idx >= 2 * 36864) return;
    const float* w = (idx < 36864) ? w0 : w1;
    int r = idx % 36864;
    cwb[idx] = f2b(w[r]);
}

// -------------------- feature transpose [b][c][t] -> bf16 [t][c] ----------
__global__ void k_tf(const float* feat, __hip_bfloat16* out, int HW, int st) {
    __shared__ float tile[32][33];
    int t0 = blockIdx.x * 32, c0 = blockIdx.y * 32, b = blockIdx.z;
    int tx = threadIdx.x, ty = threadIdx.y;
    #pragma unroll
    for (int k = 0; k < 4; k++) {
        int c = c0 + ty + k * 8;
        tile[ty + k * 8][tx] = feat[((size_t)b * Dm + c) * HW + t0 + tx];
    }
    __syncthreads();
    #pragma unroll
    for (int k = 0; k < 4; k++) {
        int t = t0 + ty + k * 8;
        out[((size_t)b * LSEQ + st + t) * Dm + c0 + tx] = f2b(tile[tx][ty + k * 8]);
    }
}

// -------------------- GN partial sums (coalesced) --------------------
__global__ __launch_bounds__(192) void k_gnp(const float* __restrict__ pre,
        float* __restrict__ part) {
    int bid = blockIdx.x;                 // 0..239
    int b = bid / 120; int r = bid % 120;
    int l = (r >= 96) ? 1 : 0; int ch = l ? (r - 96) : r;
    int start = b * LSEQ + (l ? N0 : 0) + ch * 96;
    int d = threadIdx.x;
    float s = 0.f, sq = 0.f;
    for (int t = 0; t < 96; t++) {
        float x = pre[(size_t)(start + t) * Dm + d];
        s += x; sq += x * x;
    }
    __shared__ float ls[192], lq[192];
    ls[d] = s; lq[d] = sq;
    __syncthreads();
    if (d < 32) {
        float a = 0.f, b2 = 0.f;
        #pragma unroll
        for (int j = 0; j < 6; j++) { a += ls[d * 6 + j]; b2 += lq[d * 6 + j]; }
        part[((size_t)bid * 32 + d) * 2]     = a;
        part[((size_t)bid * 32 + d) * 2 + 1] = b2;
    }
}

__global__ void k_gnf(const float* __restrict__ part, float* __restrict__ gns) {
    int bid = blockIdx.x;                 // (b,l,g): 128
    int b = bid >> 6; int l = (bid >> 5) & 1; int g = bid & 31;
    int nch = l ? 24 : 96;
    int base = b * 120 + (l ? 96 : 0);
    int tid = threadIdx.x;
    float s = 0.f, q = 0.f;
    for (int c = tid; c < nch; c += 64) {
        s += part[((size_t)(base + c) * 32 + g) * 2];
        q += part[((size_t)(base + c) * 32 + g) * 2 + 1];
    }
    for (int m = 1; m < 64; m <<= 1) { s += __shfl_xor(s, m, 64); q += __shfl_xor(q, m, 64); }
    if (tid == 0) {
        float total = (float)((l ? N1 : N0) * 6);
        float mean = s / total;
        float var = q / total - mean * mean;
        gns[bid * 2] = mean;
        gns[bid * 2 + 1] = rsqrtf(var + 1e-5f);
    }
}

// -------------------- group norm apply: OUT f32 + O bf16 + Q bf16 ----------
__global__ void k_gnnorm(const float* srcp, const float* gns,
        const float* g0, const float* b0, const float* g1, const float* b1,
        const float* pos, float* out, __hip_bfloat16* ob, __hip_bfloat16* qb) {
    int idx = blockIdx.x * 256 + threadIdx.x;
    if (idx >= Bb * LSEQ * Dm) return;
    int d = idx % Dm;
    int t = (idx / Dm) % LSEQ;
    int l = (t < N0) ? 0 : 1;
    int g = d / 6;
    int b = idx / (Dm * LSEQ);
    int sid = ((b * 2 + l) * 32 + g) * 2;
    float mean = gns[sid], rstd = gns[sid + 1];
    float gg = l ? g1[d] : g0[d];
    float bbv = l ? b1[d] : b0[d];
    float v = (srcp[idx] - mean) * rstd * gg + bbv;
    out[idx] = v;
    ob[idx] = f2b(v);
    qb[idx] = f2b(v + pos[idx - (size_t)b * LSEQ * Dm]);
}

// -------------------- bf16 MFMA GEMM (conv path) --------------------------
template<int KSTEPS>
__global__ __launch_bounds__(256) void k_gemm(
        const __hip_bfloat16* __restrict__ A,
        const __hip_bfloat16* __restrict__ Bt,
        const float* __restrict__ bias,
        float* __restrict__ Cf, int N) {
    constexpr int K = KSTEPS * 32;
    int wid = threadIdx.x >> 6, lane = threadIdx.x & 63;
    int lg = lane >> 4, lr = lane & 15;
    int row0 = blockIdx.x * 64 + wid * 16;
    int col0 = blockIdx.y * 64;
    const short* a_base = (const short*)A + (size_t)(row0 + lr) * K + lg * 8;
    const short* b_base = (const short*)Bt + (size_t)(col0 + lr) * K + lg * 8;
    f32x4 acc[4] = {};
    #pragma unroll
    for (int kk = 0; kk < KSTEPS; kk++) {
        short8 af = *(const short8*)(a_base + kk * 32);
        #pragma unroll
        for (int n = 0; n < 4; n++) {
            short8 bfr = *(const short8*)(b_base + (size_t)n * 16 * K + kk * 32);
            acc[n] = __builtin_amdgcn_mfma_f32_16x16x32_bf16(af, bfr, acc[n], 0, 0, 0);
        }
    }
    #pragma unroll
    for (int n = 0; n < 4; n++) {
        int col = col0 + n * 16 + lr;
        float bv = bias[col];
        #pragma unroll
        for (int r = 0; r < 4; r++) {
            int row = row0 + lg * 4 + r;
            Cf[(size_t)row * N + col] = acc[n][r] + bv;
        }
    }
}

// ------------- merged soaw + value-proj dispatch (BM=32, regs-held B) -----
// grid (Mrows/32, 2); 192 thr = 3 waves, wave w -> cols w*64..w*64+63
// role y==0: soaw from QB (softmax+loc epilogue); y==1: vp from OB -> VF fp32
__global__ __launch_bounds__(192) void k_soawvp(
        const __hip_bfloat16* __restrict__ QB,
        const __hip_bfloat16* __restrict__ OB,
        const __hip_bfloat16* __restrict__ BtS,
        const __hip_bfloat16* __restrict__ BtV,
        const float* __restrict__ biasS,
        const float* __restrict__ biasV,
        float* __restrict__ LOC, float* __restrict__ AW,
        float* __restrict__ VF) {
    constexpr int K = 192;
    int wid = threadIdx.x >> 6, lane = threadIdx.x & 63;
    int lg = lane >> 4, lr = lane & 15;
    int row0 = blockIdx.x * 32;
    int col0 = wid * 64;
    int role = blockIdx.y;
    const short* A  = (const short*)(role ? OB : QB);
    const short* Bt = (const short*)(role ? BtV : BtS);
    const float* bias = role ? biasV : biasS;
    short8 bw[24];
    {
        const short* b_base = Bt + (size_t)(col0 + lr) * K + lg * 8;
        #pragma unroll
        for (int n = 0; n < 4; n++)
            #pragma unroll
            for (int kk = 0; kk < 6; kk++)
                bw[n * 6 + kk] = *(const short8*)(b_base + (size_t)n * 16 * K + kk * 32);
    }
    #pragma unroll
    for (int rg = 0; rg < 2; rg++) {
        const short* a_base = A + (size_t)(row0 + rg * 16 + lr) * K + lg * 8;
        f32x4 acc[4] = {};
        #pragma unroll
        for (int kk = 0; kk < 6; kk++) {
            short8 af = *(const short8*)(a_base + kk * 32);
            #pragma unroll
            for (int n = 0; n < 4; n++)
                acc[n] = __builtin_amdgcn_mfma_f32_16x16x32_bf16(af, bw[n * 6 + kk], acc[n], 0, 0, 0);
        }
        #pragma unroll
        for (int n = 0; n < 4; n++) {
            float bv = bias[col0 + n * 16 + lr];
            #pragma unroll
            for (int r = 0; r < 4; r++) acc[n][r] += bv;
        }
        int rbase = row0 + rg * 16;
        if (role) {
            #pragma unroll
            for (int n = 0; n < 4; n++) {
                int col = col0 + n * 16 + lr;
                #pragma unroll
                for (int r = 0; r < 4; r++)
                    VF[(size_t)(rbase + lg * 4 + r) * Dm + col] = acc[n][r];
            }
        } else if (wid == 2) {
            // attn-weight softmax: head = 8 consecutive cols within this wave
            #pragma unroll
            for (int n = 0; n < 4; n++) {
                #pragma unroll
                for (int r = 0; r < 4; r++) {
                    float v = acc[n][r];
                    float m = v;
                    m = fmaxf(m, __shfl_xor(m, 1)); m = fmaxf(m, __shfl_xor(m, 2));
                    m = fmaxf(m, __shfl_xor(m, 4));
                    float e = expf(v - m);
                    float sm = e;
                    sm += __shfl_xor(sm, 1); sm += __shfl_xor(sm, 2); sm += __shfl_xor(sm, 4);
                    AW[(size_t)(rbase + lg * 4 + r) * 64 + n * 16 + lr] = e / sm;
                }
            }
        } else {
            // sampling locations (cols 0..127)
            #pragma unroll
            for (int r = 0; r < 4; r++) {
                int row = rbase + lg * 4 + r;
                int t = (row >= LSEQ) ? row - LSEQ : row;
                int rr, cc, Ht, Wt;
                if (t < N0) { Ht = 96; Wt = 96; rr = t / 96; cc = t % 96; }
                else        { Ht = 48; Wt = 48; int tl = t - N0; rr = tl / 48; cc = tl % 48; }
                float refx = (cc + 0.5f) / (float)Wt;
                float refy = (rr + 0.5f) / (float)Ht;
                #pragma unroll
                for (int n = 0; n < 4; n++) {
                    int col = col0 + n * 16 + lr;
                    int j = col >> 1, comp = col & 1;
                    float sc = (j & 4) ? 48.f : 96.f;
                    LOC[(size_t)row * 128 + col] = (comp ? refy : refx) + acc[n][r] / sc;
                }
            }
        }
    }
}

// ------------- fused tail: op GEMM + LN1 + FFN1 + FFN2 + LN2 + Q ----------
// BM=32, shared-B interleave: each streamed B-frag feeds 2 row-groups.
// grid (Mrows/32); 256 thr = 4 waves. op/ffn2: wave cols w*48; ffn1: w*64.
// LN1 output kept in registers for the phase-C residual (same lane mapping).
__global__ __launch_bounds__(256) void k_tail(
        const __hip_bfloat16* __restrict__ ATT,
        const __hip_bfloat16* __restrict__ BtOp, const float* __restrict__ bOp,
        const __hip_bfloat16* __restrict__ Bt1, const float* __restrict__ b1,
        const __hip_bfloat16* __restrict__ Bt2, const float* __restrict__ b2,
        const float* __restrict__ g1, const float* __restrict__ t1,
        const float* __restrict__ g2, const float* __restrict__ t2,
        const float* __restrict__ pos,
        float* __restrict__ OUTp, __hip_bfloat16* __restrict__ ob,
        __hip_bfloat16* __restrict__ qb) {
    __shared__ __align__(16) short ybf[32][200];
    __shared__ __align__(16) short hid[32][264];
    __shared__ float ps[4][32], pq[4][32];
    int tid = threadIdx.x;
    int wid = tid >> 6, lane = tid & 63, lg = lane >> 4, lr = lane & 15;
    int row0 = blockIdx.x * 32;
    float yres[2][3][4];
    // ---- phase A: op GEMM (K=192, N=192) + bias + residual + LN1 ----
    {
        float resid[2][3][4];
        #pragma unroll
        for (int rg = 0; rg < 2; rg++)
            #pragma unroll
            for (int n = 0; n < 3; n++) {
                int col = wid * 48 + n * 16 + lr;
                #pragma unroll
                for (int r = 0; r < 4; r++)
                    resid[rg][n][r] = OUTp[(size_t)(row0 + rg * 16 + lg * 4 + r) * Dm + col];
            }
        const short* a0 = (const short*)ATT + (size_t)(row0 + lr) * 192 + lg * 8;
        const short* a1 = (const short*)ATT + (size_t)(row0 + 16 + lr) * 192 + lg * 8;
        const short* b_base = (const short*)BtOp + (size_t)(wid * 48 + lr) * 192 + lg * 8;
        f32x4 acc[2][3] = {};
        #pragma unroll
        for (int kk = 0; kk < 6; kk++) {
            short8 af0 = *(const short8*)(a0 + kk * 32);
            short8 af1 = *(const short8*)(a1 + kk * 32);
            #pragma unroll
            for (int n = 0; n < 3; n++) {
                short8 bfr = *(const short8*)(b_base + (size_t)n * 16 * 192 + kk * 32);
                acc[0][n] = __builtin_amdgcn_mfma_f32_16x16x32_bf16(af0, bfr, acc[0][n], 0, 0, 0);
                acc[1][n] = __builtin_amdgcn_mfma_f32_16x16x32_bf16(af1, bfr, acc[1][n], 0, 0, 0);
            }
        }
        #pragma unroll
        for (int rg = 0; rg < 2; rg++) {
            float s[4] = {0.f, 0.f, 0.f, 0.f}, q[4] = {0.f, 0.f, 0.f, 0.f};
            #pragma unroll
            for (int n = 0; n < 3; n++) {
                int col = wid * 48 + n * 16 + lr;
                float bv = bOp[col];
                #pragma unroll
                for (int r = 0; r < 4; r++) {
                    float v = acc[rg][n][r] + bv + resid[rg][n][r];
                    acc[rg][n][r] = v;
                    s[r] += v; q[r] += v * v;
                }
            }
            #pragma unroll
            for (int r = 0; r < 4; r++) {
                #pragma unroll
                for (int m = 1; m < 16; m <<= 1) {
                    s[r] += __shfl_xor(s[r], m); q[r] += __shfl_xor(q[r], m);
                }
            }
            if (lr == 0) {
                #pragma unroll
                for (int r = 0; r < 4; r++) {
                    ps[wid][rg * 16 + lg * 4 + r] = s[r];
                    pq[wid][rg * 16 + lg * 4 + r] = q[r];
                }
            }
        }
        __syncthreads();
        #pragma unroll
        for (int rg = 0; rg < 2; rg++) {
            float mean[4], rstd[4];
            #pragma unroll
            for (int r = 0; r < 4; r++) {
                int rl = rg * 16 + lg * 4 + r;
                float S = ps[0][rl] + ps[1][rl] + ps[2][rl] + ps[3][rl];
                float Q = pq[0][rl] + pq[1][rl] + pq[2][rl] + pq[3][rl];
                mean[r] = S * (1.f / Dm);
                float var = Q * (1.f / Dm) - mean[r] * mean[r];
                rstd[r] = rsqrtf(var + 1e-5f);
            }
            #pragma unroll
            for (int n = 0; n < 3; n++) {
                int col = wid * 48 + n * 16 + lr;
                float gg = g1[col], bb = t1[col];
                #pragma unroll
                for (int r = 0; r < 4; r++) {
                    float y = (acc[rg][n][r] - mean[r]) * rstd[r] * gg + bb;
                    yres[rg][n][r] = y;
                    ybf[rg * 16 + lg * 4 + r][col] = (short)f2bu(y);
                }
            }
        }
        __syncthreads();
    }
    // ---- phase B: ffn1 (K=192 from ybf, N=256) + ReLU -> hid ----
    {
        const short* b_base = (const short*)Bt1 + (size_t)(wid * 64 + lr) * 192 + lg * 8;
        f32x4 acc[2][4] = {};
        #pragma unroll
        for (int kk = 0; kk < 6; kk++) {
            short8 af0 = *(const short8*)&ybf[lr][lg * 8 + kk * 32];
            short8 af1 = *(const short8*)&ybf[16 + lr][lg * 8 + kk * 32];
            #pragma unroll
            for (int n = 0; n < 4; n++) {
                short8 bfr = *(const short8*)(b_base + (size_t)n * 16 * 192 + kk * 32);
                acc[0][n] = __builtin_amdgcn_mfma_f32_16x16x32_bf16(af0, bfr, acc[0][n], 0, 0, 0);
                acc[1][n] = __builtin_amdgcn_mfma_f32_16x16x32_bf16(af1, bfr, acc[1][n], 0, 0, 0);
            }
        }
        #pragma unroll
        for (int rg = 0; rg < 2; rg++)
            #pragma unroll
            for (int n = 0; n < 4; n++) {
                int col = wid * 64 + n * 16 + lr;
                float bv = b1[col];
                #pragma unroll
                for (int r = 0; r < 4; r++)
                    hid[rg * 16 + lg * 4 + r][col] = (short)f2bu(fmaxf(acc[rg][n][r] + bv, 0.f));
            }
        __syncthreads();
    }
    // ---- phase C: ffn2 (K=256 from hid, N=192) + resid(yres) + LN2 + out --
    {
        const short* b_base = (const short*)Bt2 + (size_t)(wid * 48 + lr) * 256 + lg * 8;
        f32x4 acc[2][3] = {};
        #pragma unroll
        for (int kk = 0; kk < 8; kk++) {
            short8 af0 = *(const short8*)&hid[lr][lg * 8 + kk * 32];
            short8 af1 = *(const short8*)&hid[16 + lr][lg * 8 + kk * 32];
            #pragma unroll
            for (int n = 0; n < 3; n++) {
                short8 bfr = *(const short8*)(b_base + (size_t)n * 16 * 256 + kk * 32);
                acc[0][n] = __builtin_amdgcn_mfma_f32_16x16x32_bf16(af0, bfr, acc[0][n], 0, 0, 0);
                acc[1][n] = __builtin_amdgcn_mfma_f32_16x16x32_bf16(af1, bfr, acc[1][n], 0, 0, 0);
            }
        }
        #pragma unroll
        for (int rg = 0; rg < 2; rg++) {
            float s[4] = {0.f, 0.f, 0.f, 0.f}, q[4] = {0.f, 0.f, 0.f, 0.f};
            #pragma unroll
            for (int n = 0; n < 3; n++) {
                int col = wid * 48 + n * 16 + lr;
                float bv = b2[col];
                #pragma unroll
                for (int r = 0; r < 4; r++) {
                    float v = acc[rg][n][r] + bv + yres[rg][n][r];
                    acc[rg][n][r] = v;
                    s[r] += v; q[r] += v * v;
                }
            }
            #pragma unroll
            for (int r = 0; r < 4; r++) {
                #pragma unroll
                for (int m = 1; m < 16; m <<= 1) {
                    s[r] += __shfl_xor(s[r], m); q[r] += __shfl_xor(q[r], m);
                }
            }
            if (lr == 0) {
                #pragma unroll
                for (int r = 0; r < 4; r++) {
                    ps[wid][rg * 16 + lg * 4 + r] = s[r];
                    pq[wid][rg * 16 + lg * 4 + r] = q[r];
                }
            }
        }
        __syncthreads();
        #pragma unroll
        for (int rg = 0; rg < 2; rg++) {
            float mean[4], rstd[4];
            #pragma unroll
            for (int r = 0; r < 4; r++) {
                int rl = rg * 16 + lg * 4 + r;
                float S = ps[0][rl] + ps[1][rl] + ps[2][rl] + ps[3][rl];
                float Q = pq[0][rl] + pq[1][rl] + pq[2][rl] + pq[3][rl];
                mean[r] = S * (1.f / Dm);
                float var = Q * (1.f / Dm) - mean[r] * mean[r];
                rstd[r] = rsqrtf(var + 1e-5f);
            }
            #pragma unroll
            for (int n = 0; n < 3; n++) {
                int col = wid * 48 + n * 16 + lr;
                float gg = g2[col], bb = t2[col];
                #pragma unroll
                for (int r = 0; r < 4; r++) {
                    int row = row0 + rg * 16 + lg * 4 + r;
                    size_t o = (size_t)row * Dm + col;
                    float y = (acc[rg][n][r] - mean[r]) * rstd[r] * gg + bb;
                    OUTp[o] = y;
                    ob[o] = f2b(y);
                    int tp = (row >= LSEQ) ? row - LSEQ : row;
                    qb[o] = f2b(y + pos[(size_t)tp * Dm + col]);
                }
            }
        }
    }
}

// -------------------- deformable sampling (fp32 V, vectorized) -------------
// block = 192 thr = 4 tokens x 48 lanes (8 heads x 6 d-quads)
__global__ __launch_bounds__(192) void k_sample(const float* __restrict__ V,
        const float* __restrict__ LOC, const float* __restrict__ AW,
        __hip_bfloat16* __restrict__ ATT) {
    __shared__ float aw_s[4][64];
    __shared__ float loc_s[4][128];
    int tid = threadIdx.x;
    int tg0 = blockIdx.x * 4;
    for (int idx = tid; idx < 256; idx += 192)
        aw_s[idx >> 6][idx & 63] = AW[(size_t)tg0 * 64 + idx];
    for (int idx = tid; idx < 512; idx += 192)
        loc_s[idx >> 7][idx & 127] = LOC[(size_t)tg0 * 128 + idx];
    __syncthreads();
    int tt = tid / 48, lane = tid - tt * 48;
    int h = lane / 6, dq = lane - h * 6;
    int tg = tg0 + tt;
    int b = (tg >= LSEQ) ? 1 : 0;
    const float* vb = V + (size_t)b * LSEQ * Dm + h * HDd + dq * 4;
    float a0 = 0.f, a1 = 0.f, a2 = 0.f, a3 = 0.f;
    #pragma unroll
    for (int lp = 0; lp < 8; lp++) {
        int l = lp >> 2;
        int Wl = l ? 48 : 96, Hl = l ? 48 : 96, st = l ? N0 : 0;
        float a  = aw_s[tt][h * 8 + lp];
        float lx = loc_s[tt][(h * 8 + lp) * 2];
        float ly = loc_s[tt][(h * 8 + lp) * 2 + 1];
        float x = lx * (float)Wl - 0.5f, y = ly * (float)Hl - 0.5f;
        float x0f = floorf(x), y0f = floorf(y);
        float wx = x - x0f, wy = y - y0f;
        int x0 = (int)x0f, y0 = (int)y0f;
        #pragma unroll
        for (int cy = 0; cy < 2; cy++) {
            int yi = y0 + cy;
            float wyv = cy ? wy : 1.f - wy;
            bool vy = (yi >= 0) && (yi < Hl);
            int yc = min(max(yi, 0), Hl - 1);
            #pragma unroll
            for (int cx = 0; cx < 2; cx++) {
                int xi = x0 + cx;
                float wv = (cx ? wx : 1.f - wx) * wyv;
                bool ok = vy && (xi >= 0) && (xi < Wl);
                int xc = min(max(xi, 0), Wl - 1);
                float cw = ok ? a * wv : 0.f;
                float4 g4 = *(const float4*)(vb + (size_t)(st + yc * Wl + xc) * Dm);
                a0 += cw * g4.x; a1 += cw * g4.y;
                a2 += cw * g4.z; a3 += cw * g4.w;
            }
        }
    }
    ushort4 o4;
    o4.x = f2bu(a0); o4.y = f2bu(a1); o4.z = f2bu(a2); o4.w = f2bu(a3);
    *(ushort4*)((unsigned short*)ATT + (size_t)tg * Dm + h * HDd + dq * 4) = o4;
}

// -------------------- final [t][d] -> [d][t] tiled transpose ---------------
__global__ void k_outt(const float* __restrict__ out, float* __restrict__ dst,
        int HW, int st) {
    __shared__ float tile[32][33];
    int t0 = blockIdx.x * 32, d0 = blockIdx.y * 32, b = blockIdx.z;
    int tx = threadIdx.x, ty = threadIdx.y;
    #pragma unroll
    for (int k = 0; k < 4; k++) {
        int t = t0 + ty + k * 8;
        tile[ty + k * 8][tx] = out[((size_t)b * LSEQ + st + t) * Dm + d0 + tx];
    }
    __syncthreads();
    #pragma unroll
    for (int k = 0; k < 4; k++) {
        int d = d0 + ty + k * 8;
        dst[((size_t)b * Dm + d) * HW + t0 + tx] = tile[tx][ty + k * 8];
    }
}

extern "C" void kernel_launch(void* const* d_in, const int* in_sizes, int n_in,
                              void* d_out, int out_size, void* d_ws, size_t ws_size,
                              hipStream_t stream) {
    (void)in_sizes; (void)n_in; (void)out_size; (void)ws_size;
    const float* feat0   = (const float*)d_in[0];
    const float* feat1   = (const float*)d_in[1];
    const float* proj_w0 = (const float*)d_in[3];
    const float* proj_b0 = (const float*)d_in[4];
    const float* gn_g0   = (const float*)d_in[5];
    const float* gn_b0   = (const float*)d_in[6];
    const float* proj_w1 = (const float*)d_in[7];
    const float* proj_b1 = (const float*)d_in[8];
    const float* gn_g1   = (const float*)d_in[9];
    const float* gn_b1   = (const float*)d_in[10];
    const float* level_embed = (const float*)d_in[11];
    const float* so_W = (const float*)d_in[12];
    const float* so_b = (const float*)d_in[13];
    const float* aw_W = (const float*)d_in[14];
    const float* aw_b = (const float*)d_in[15];
    const float* vp_W = (const float*)d_in[16];
    const float* vp_b = (const float*)d_in[17];
    const float* op_W = (const float*)d_in[18];
    const float* op_b = (const float*)d_in[19];
    const float* ln1_g = (const float*)d_in[20];
    const float* ln1_b = (const float*)d_in[21];
    const float* l1_W = (const float*)d_in[22];
    const float* l1_b = (const float*)d_in[23];
    const float* l2_W = (const float*)d_in[24];
    const float* l2_b = (const float*)d_in[25];
    const float* ln2_g = (const float*)d_in[26];
    const float* ln2_b = (const float*)d_in[27];

    float* ws   = (float*)d_ws;
    float* OUT  = ws + F_OUT;
    float* PRE  = ws + F_PRE;          // conv-out / GN src; in-loop: V fp32
    float* POS  = ws + F_POS;
    float* LOC  = ws + F_LOC;
    float* AWp  = ws + F_AW;
    __hip_bfloat16* QB  = (__hip_bfloat16*)(ws + F_QB);
    __hip_bfloat16* OB  = (__hip_bfloat16*)(ws + F_OB);
    __hip_bfloat16* AH  = (__hip_bfloat16*)(ws + F_AH);   // ATT
    __hip_bfloat16* WT16 = (__hip_bfloat16*)(ws + F_WT16);
    float* BC   = ws + F_BC;
    float* GNS  = ws + F_GNS;
    // early-phase aliases (consumed before the layer loop)
    __hip_bfloat16* FEATB = (__hip_bfloat16*)(ws + F_LOC);
    __hip_bfloat16* CWB   = (__hip_bfloat16*)(ws + F_AW);
    float* GPART = ws + F_AH;                              // 240*32*2 floats

    k_pos<<<(LSEQ * Dm + 255) / 256, 256, 0, stream>>>(POS, level_embed);
    k_prep<<<(6 * WL_STRIDE + 255) / 256, 256, 0, stream>>>(so_W, aw_W, vp_W, op_W,
        l1_W, l2_W, so_b, aw_b, WT16, BC);
    k_prepc<<<(2 * 36864 + 255) / 256, 256, 0, stream>>>(proj_w0, proj_w1, CWB);
    k_tf<<<dim3(N0 / 32, 6, 2), dim3(32, 8), 0, stream>>>(feat0, FEATB, N0, 0);
    k_tf<<<dim3(N1 / 32, 6, 2), dim3(32, 8), 0, stream>>>(feat1, FEATB, N1, N0);
    for (int b = 0; b < 2; b++) {
        k_gemm<6><<<dim3(N0 / 64, 3), 256, 0, stream>>>(
            FEATB + (size_t)b * LSEQ * Dm, CWB, proj_b0,
            PRE + (size_t)b * LSEQ * Dm, Dm);
        k_gemm<6><<<dim3(N1 / 64, 3), 256, 0, stream>>>(
            FEATB + ((size_t)b * LSEQ + N0) * Dm, CWB + 36864, proj_b1,
            PRE + ((size_t)b * LSEQ + N0) * Dm, Dm);
    }
    k_gnp<<<240, 192, 0, stream>>>(PRE, GPART);
    k_gnf<<<128, 64, 0, stream>>>(GPART, GNS);
    k_gnnorm<<<(Bb * LSEQ * Dm + 255) / 256, 256, 0, stream>>>(PRE, GNS,
        gn_g0, gn_b0, gn_g1, gn_b1, POS, OUT, OB, QB);

    for (int i = 0; i < 6; i++) {
        const __hip_bfloat16* WL = WT16 + (size_t)i * WL_STRIDE;
        k_soawvp<<<dim3(Mrows / 32, 2), 192, 0, stream>>>(
            QB, OB, WL + WL_SOAW, WL + WL_VP, BC + i * 192,
            vp_b + (size_t)i * Dm, LOC, AWp, PRE);
        k_sample<<<Mrows / 4, 192, 0, stream>>>(PRE, LOC, AWp, AH);
        k_tail<<<Mrows / 32, 256, 0, stream>>>(
            AH, WL + WL_OP, op_b + (size_t)i * Dm,
            WL + WL_L1, l1_b + (size_t)i * FFD,
            WL + WL_L2, l2_b + (size_t)i * Dm,
            ln1_g + (size_t)i * Dm, ln1_b + (size_t)i * Dm,
            ln2_g + (size_t)i * Dm, ln2_b + (size_t)i * Dm, POS,
            OUT, OB, QB);
    }
    k_outt<<<dim3(N0 / 32, 6, 2), dim3(32, 8), 0, stream>>>(OUT, (float*)d_out, N0, 0);
    k_outt<<<dim3(N1 / 32, 6, 2), dim3(32, 8), 0, stream>>>(OUT,
        (float*)d_out + (size_t)Bb * Dm * N0, N1, N0);
}